// Round 5
// baseline (504.607 us; speedup 1.0000x reference)
//
#include <hip/hip_runtime.h>

// GAT 3-layer on MI355X — bf16/MFMA pipeline, R10: VALU-lean aggregation.
//   CSR build: hist -> scan(+last-block bsum scan) -> scan3(+bucket cursors) ->
//              bucket-partition (packed 4B pairs) -> per-bucket scatter
//              (single block per bucket => single-XCD contiguous writes)
//   prep_w: bf16 weight transposes + waS/waD = W@a_s precompute (+ cnt/ticket 0)
//   gemm_pre_fused (tiles folded into build kernels): h0 = x@lw+b stays in
//        LDS; immediately h'1 = h0@W1 + attn dots -> bufB (fp32), hsB/hdB.
//   fused_ag x2: aggregate (fp32 rows, simple loop) -> bf16 LDS tile ->
//        next-layer GEMM stripe + waS-trick dots -> fp32 C.
//   gat_agg_final: final aggregate + bias + L2 normalize -> fp32 d_out.
// R10 changes (R9 counters: fused_ag VALUBusy 66%, MfmaUtil 0.5%, HBM 17% —
// VALU-bound): (a) h rows stored fp32 — kills 8 unpack ops/round in gathers
// (bf16 kept only for MFMA fragments); (b) software pipeline deleted (R6
// proved it null; its muxes/rotates were pure VALU cost); (c) 32-bit gather
// address math. FETCH doubles (~30% HBM) — 5x headroom there.

constexpr float NEG_SLOPE = 0.2f;
#define BKT_SHIFT 9                // 512 nodes per bucket
#define BKT_N     512
#define PCHUNK    2048             // edges staged per partition block
#define SRC_BITS  17               // N=100000 < 2^17

typedef __attribute__((ext_vector_type(8))) short bf16x8;
typedef __attribute__((ext_vector_type(4))) float f32x4;

__device__ inline ushort f2bf(float x) {
    union { float f; uint u; } v; v.f = x;
    return (ushort)((v.u + 0x7FFFu + ((v.u >> 16) & 1u)) >> 16);
}
__device__ inline void bf2f(uint u, float& lo, float& hi) {
    union { uint u; float f; } a, b;
    a.u = u << 16; b.u = u & 0xFFFF0000u;
    lo = a.f; hi = b.f;
}
__device__ inline uint pk(float a, float b) {
    return (uint)f2bf(a) | ((uint)f2bf(b) << 16);
}

struct PreArgs {
    const float* x; const ushort* lwT; const float* lin_b;
    const ushort* w1T; const float* a1s; const float* a1d;
    float* C; float* hs; float* hd; int M;
};

// ---------------- weight prep: bf16 transpose + waS/waD + cnt/ticket zero ----
__global__ __launch_bounds__(256) void prep_w(
    const float* __restrict__ lw, const float* __restrict__ w1,
    const float* __restrict__ w2, const float* __restrict__ w3,
    const float* __restrict__ a2s, const float* __restrict__ a2d,
    const float* __restrict__ a3s, const float* __restrict__ a3d,
    ushort* __restrict__ lwT, ushort* __restrict__ w1T,
    ushort* __restrict__ w2T, ushort* __restrict__ w3T,
    float* __restrict__ wvec,
    int* __restrict__ cnt, int* __restrict__ ticket, int n)
{
    const int i = blockIdx.x * 256 + threadIdx.x;
    if (i < n) cnt[i] = 0;
    if (i == 0) *ticket = 0;
    if (i < 64 * 256) {                 // lwT[n][k] = lw[k][n], K=256
        const int nn = i >> 8, k = i & 255;
        lwT[i] = f2bf(lw[k * 64 + nn]);
    } else if (i < 64 * 256 + 4096) {   // wT[n][k] = w[k][n], K=64
        const int j = i - 64 * 256;
        const int nn = j >> 6, k = j & 63;
        w1T[j] = f2bf(w1[k * 64 + nn]);
        w2T[j] = f2bf(w2[k * 64 + nn]);
        w3T[j] = f2bf(w3[k * 64 + nn]);
    } else if (i < 64 * 256 + 4096 + 256) {
        // wvec[p][k] = sum_n W[k][n] * a[n]; p: 0=w2·a2s 1=w2·a2d 2=w3·a3s 3=w3·a3d
        const int j = i - 64 * 256 - 4096;
        const int p = j >> 6, k = j & 63;
        const float* Wp = (p < 2) ? w2 : w3;
        const float* vp = (p == 0) ? a2s : (p == 1) ? a2d : (p == 2) ? a3s : a3d;
        float s = 0.f;
        #pragma unroll
        for (int t = 0; t < 64; ++t) s += Wp[k * 64 + t] * vp[t];
        wvec[p * 64 + k] = s;
    }
}

// ------- gemm_pre_fused tile: h'1 = (x@lw+b)@W1 + attn dots, per 64 rows -----
__device__ __forceinline__ void gemm_pre_fused(const PreArgs& pa, int tile)
{
    __shared__ __align__(16) ushort ldsA[4][8][16][8];   // [wave][kblk][row][8]
    __shared__ __align__(16) float ctileF[4][16][64];
    const int tid = threadIdx.x;
    const int w = tid >> 6, lane = tid & 63;
    const int rw0 = (tile * 4 + w) * 16;
    if (rw0 >= pa.M) return;
    const int c = lane & 15, q = lane >> 4;

    // ---- stage 1: h0 = x @ lin_w (+ lin_b) ----
    const float* ap = pa.x + (size_t)(rw0 + c) * 256 + q * 8;
    float4 pv[16];
    #pragma unroll
    for (int s = 0; s < 8; ++s) {
        pv[2 * s]     = *(const float4*)(ap + s * 32);
        pv[2 * s + 1] = *(const float4*)(ap + s * 32 + 4);
    }
    f32x4 acc[4];
    #pragma unroll
    for (int t = 0; t < 4; ++t) acc[t] = (f32x4){0.f, 0.f, 0.f, 0.f};
    #pragma unroll
    for (int s = 0; s < 8; ++s) {
        const float4 p0 = pv[2 * s];
        const float4 p1 = pv[2 * s + 1];
        bf16x8 af;
        af[0] = (short)f2bf(p0.x); af[1] = (short)f2bf(p0.y);
        af[2] = (short)f2bf(p0.z); af[3] = (short)f2bf(p0.w);
        af[4] = (short)f2bf(p1.x); af[5] = (short)f2bf(p1.y);
        af[6] = (short)f2bf(p1.z); af[7] = (short)f2bf(p1.w);
        #pragma unroll
        for (int t = 0; t < 4; ++t) {
            const bf16x8 bf = *(const bf16x8*)(pa.lwT + (size_t)(t * 16 + c) * 256 + s * 32 + q * 8);
            acc[t] = __builtin_amdgcn_mfma_f32_16x16x32_bf16(af, bf, acc[t], 0, 0, 0);
        }
    }
    // round h0+bias into fragment-layout LDS (row=q*4+r, col=16t+c)
    #pragma unroll
    for (int t = 0; t < 4; ++t) {
        const float bv = pa.lin_b[t * 16 + c];
        const int kb = 2 * t + (c >> 3);
        const int e  = c & 7;
        #pragma unroll
        for (int r = 0; r < 4; ++r)
            ldsA[w][kb][q * 4 + r][e] = f2bf(acc[t][r] + bv);
    }

    // ---- stage 2: h'1 = h0 @ W1 (+ dots) ----  (same-wave LDS RAW: DS in-order)
    const bf16x8 a0 = *(const bf16x8*)&ldsA[w][q][c][0];
    const bf16x8 a1 = *(const bf16x8*)&ldsA[w][q + 4][c][0];
    f32x4 acc2[4];
    #pragma unroll
    for (int t = 0; t < 4; ++t) {
        const ushort* bp = pa.w1T + (size_t)(t * 16 + c) * 64 + q * 8;
        const bf16x8 b0 = *(const bf16x8*)(bp);
        const bf16x8 b1 = *(const bf16x8*)(bp + 32);
        f32x4 a = (f32x4){0.f, 0.f, 0.f, 0.f};
        a = __builtin_amdgcn_mfma_f32_16x16x32_bf16(a0, b0, a, 0, 0, 0);
        a = __builtin_amdgcn_mfma_f32_16x16x32_bf16(a1, b1, a, 0, 0, 0);
        acc2[t] = a;
    }
    // attn dots (from fp32 C, identical to old gemm_layer)
    float ps[4] = {0.f, 0.f, 0.f, 0.f}, pd[4] = {0.f, 0.f, 0.f, 0.f};
    #pragma unroll
    for (int t = 0; t < 4; ++t) {
        const float as = pa.a1s[t * 16 + c], ad = pa.a1d[t * 16 + c];
        #pragma unroll
        for (int r = 0; r < 4; ++r) {
            ps[r] = fmaf(acc2[t][r], as, ps[r]);
            pd[r] = fmaf(acc2[t][r], ad, pd[r]);
        }
    }
    #pragma unroll
    for (int r = 0; r < 4; ++r) {
        #pragma unroll
        for (int off = 1; off < 16; off <<= 1) {
            ps[r] += __shfl_xor(ps[r], off);
            pd[r] += __shfl_xor(pd[r], off);
        }
    }
    if (c == 0) {
        #pragma unroll
        for (int r = 0; r < 4; ++r) {
            pa.hs[rw0 + q * 4 + r] = ps[r];
            pa.hd[rw0 + q * 4 + r] = pd[r];
        }
    }
    // fp32 store via per-wave LDS transpose
    #pragma unroll
    for (int t = 0; t < 4; ++t)
        #pragma unroll
        for (int r = 0; r < 4; ++r)
            ctileF[w][q * 4 + r][t * 16 + c] = acc2[t][r];
    const int row = lane >> 2, eo = (lane & 3) * 16;
    float* op = pa.C + (size_t)(rw0 + row) * 64 + eo;
    #pragma unroll
    for (int k = 0; k < 4; ++k)
        *(float4*)(op + k * 4) = *(const float4*)&ctileF[w][row][eo + k * 4];
}

// ---------------- CSR build --------------------------------------------------
__global__ __launch_bounds__(256) void edge_hist(
    const int* __restrict__ dst, int* __restrict__ cnt, int e)
{
    const int i0 = (blockIdx.x * 256 + threadIdx.x) * 4;
    if (i0 + 3 < e) {
        const int4 d = *(const int4*)(dst + i0);
        atomicAdd(&cnt[d.x], 1); atomicAdd(&cnt[d.y], 1);
        atomicAdd(&cnt[d.z], 1); atomicAdd(&cnt[d.w], 1);
    } else {
        for (int k = i0; k < e; ++k) atomicAdd(&cnt[dst[k]], 1);
    }
}

__global__ __launch_bounds__(256) void scan1_tiles(
    const int* __restrict__ cnt, int* __restrict__ out,
    int* __restrict__ bsum, int* __restrict__ ticket, int n, int nblk,
    PreArgs pa, int tile0)
{
    __shared__ int wsum[4];
    __shared__ int amLastS;
    if ((int)blockIdx.x >= nblk) {
        gemm_pre_fused(pa, tile0 + (int)blockIdx.x - nblk);
        return;
    }
    const int tid  = threadIdx.x;
    const int lane = tid & 63;
    const int w    = tid >> 6;
    const int base = blockIdx.x * 1024;
    int vals[4];
    int tsum = 0;
    #pragma unroll
    for (int i = 0; i < 4; ++i) {
        const int idx = base + tid * 4 + i;
        vals[i] = (idx < n) ? cnt[idx] : 0;
        tsum += vals[i];
    }
    int x1 = tsum;
    #pragma unroll
    for (int off = 1; off < 64; off <<= 1) {
        const int y = __shfl_up(x1, off);
        if (lane >= off) x1 += y;
    }
    if (lane == 63) wsum[w] = x1;
    __syncthreads();
    int wofs = 0;
    for (int k = 0; k < w; ++k) wofs += wsum[k];
    int excl = wofs + x1 - tsum;
    #pragma unroll
    for (int i = 0; i < 4; ++i) {
        const int idx = base + tid * 4 + i;
        if (idx < n) out[idx] = excl;
        excl += vals[i];
    }
    if (tid == 255) {
        bsum[blockIdx.x] = wofs + x1;
        __threadfence();                       // release bsum write
        amLastS = (atomicAdd(ticket, 1) == nblk - 1) ? 1 : 0;
    }
    __syncthreads();
    if (amLastS) {                             // last block scans bsum[nblk]
        __threadfence();                       // acquire others' bsum writes
        const int v2 = (tid < nblk) ? bsum[tid] : 0;
        int x2 = v2;
        #pragma unroll
        for (int off = 1; off < 64; off <<= 1) {
            const int y = __shfl_up(x2, off);
            if (lane >= off) x2 += y;
        }
        if (lane == 63) wsum[w] = x2;
        __syncthreads();
        int c2 = 0;
        for (int k = 0; k < w; ++k) c2 += wsum[k];
        if (tid < nblk) bsum[tid] = c2 + x2 - v2;
    }
}

__global__ __launch_bounds__(256) void scan3_tiles(
    int* __restrict__ out, const int* __restrict__ bsum,
    int* __restrict__ gcur, int n, int total, int s3b,
    PreArgs pa, int tile0)
{
    if ((int)blockIdx.x >= s3b) {
        gemm_pre_fused(pa, tile0 + (int)blockIdx.x - s3b);
        return;
    }
    const int idx = blockIdx.x * 256 + threadIdx.x;
    if (idx < n) {
        const int v = out[idx] + bsum[idx >> 10];
        out[idx] = v;
        if ((idx & (BKT_N - 1)) == 0) gcur[idx >> BKT_SHIFT] = v;
    }
    if (idx == 0) out[n] = total;
}

__global__ __launch_bounds__(256) void part_tiles(
    const int* __restrict__ src, const int* __restrict__ dst,
    int* __restrict__ gcursor, int* __restrict__ pairs, int e, int nb, int pb,
    PreArgs pa, int tile0)
{
    __shared__ int stage[PCHUNK];
    __shared__ unsigned char sbkt[PCHUNK];
    __shared__ int lcnt[256];
    __shared__ int lstart[256];
    __shared__ int lfill[256];
    __shared__ int gbase[256];
    __shared__ int wsum[4];

    if ((int)blockIdx.x >= pb) {
        gemm_pre_fused(pa, tile0 + (int)blockIdx.x - pb);
        return;
    }

    const int tid  = threadIdx.x;
    const int lane = tid & 63;
    const int w    = tid >> 6;
    const int base = blockIdx.x * PCHUNK;
    const int cnt_here = min(PCHUNK, e - base);

    lcnt[tid] = 0; lfill[tid] = 0;
    __syncthreads();

    for (int i = tid; i < cnt_here; i += 256)
        atomicAdd(&lcnt[dst[base + i] >> BKT_SHIFT], 1);
    __syncthreads();

    const int v = lcnt[tid];
    int x1 = v;
    #pragma unroll
    for (int off = 1; off < 64; off <<= 1) {
        const int y = __shfl_up(x1, off);
        if (lane >= off) x1 += y;
    }
    if (lane == 63) wsum[w] = x1;
    __syncthreads();
    int carry = 0;
    for (int k = 0; k < w; ++k) carry += wsum[k];
    lstart[tid] = carry + x1 - v;
    if (tid < nb && v > 0) gbase[tid] = atomicAdd(&gcursor[tid], v);
    __syncthreads();

    for (int i = tid; i < cnt_here; i += 256) {
        const int d = dst[base + i];
        const int s = src[base + i];
        const int b = d >> BKT_SHIFT;
        const int p = lstart[b] + atomicAdd(&lfill[b], 1);
        stage[p] = ((d & (BKT_N - 1)) << SRC_BITS) | s;
        sbkt[p]  = (unsigned char)b;
    }
    __syncthreads();

    for (int t = tid; t < cnt_here; t += 256) {
        const int b = sbkt[t];
        pairs[gbase[b] + (t - lstart[b])] = stage[t];
    }
}

__global__ __launch_bounds__(256) void scat_tiles(
    const int* __restrict__ pairs, const int* __restrict__ offs,
    int* __restrict__ ssrc, int n, int sb,
    PreArgs pa, int tile0)
{
    __shared__ int pos[BKT_N];
    if ((int)blockIdx.x >= sb) {
        gemm_pre_fused(pa, tile0 + (int)blockIdx.x - sb);
        return;
    }
    const int node0 = blockIdx.x << BKT_SHIFT;
    const int node1 = min(n, node0 + BKT_N);
    const int tid = threadIdx.x;
    for (int i = tid; i < node1 - node0; i += 256) pos[i] = offs[node0 + i];
    __syncthreads();
    const int e0 = offs[node0];
    const int e1 = offs[node1];
    for (int j = e0 + tid; j < e1; j += 256) {
        const int pr = pairs[j];
        const int p = atomicAdd(&pos[pr >> SRC_BITS], 1);
        ssrc[p] = pr & ((1 << SRC_BITS) - 1);
    }
}

// -------- fused aggregate + next-layer GEMM ----------------------------------
// Block = 16 nodes (4 waves x 4 nodes). Gather reads fp32 rows (no unpack),
// simple loop (no SW pipeline — R6 proved null), 32-bit addressing.
__global__ __launch_bounds__(256) void fused_ag(
    const float* __restrict__ hp, const float* __restrict__ hsIn,
    const float* __restrict__ hdIn, const int* __restrict__ offs,
    const int* __restrict__ ssrc, const float* __restrict__ bias,
    const ushort* __restrict__ WT, const float* __restrict__ waS,
    const float* __restrict__ waD,
    float* __restrict__ C, float* __restrict__ hsOut, float* __restrict__ hdOut,
    int n)
{
    __shared__ __align__(16) ushort ldsA[8][16][8];   // [kblk][row][8] bf16
    __shared__ __align__(16) float ldsC[16][68];
    const int tid  = threadIdx.x;
    const int w    = tid >> 6, lane = tid & 63;
    const int rw0  = blockIdx.x * 16;
    const int sub  = lane >> 3;
    const int f0   = (lane & 7) * 8;

    const float4 bv0 = *(const float4*)(bias + f0);
    const float4 bv1 = *(const float4*)(bias + f0 + 4);
    const float bb[8] = {bv0.x, bv0.y, bv0.z, bv0.w, bv1.x, bv1.y, bv1.z, bv1.w};
    float ws8[8], wd8[8];
    {
        const float4 s0 = *(const float4*)(waS + f0);
        const float4 s1 = *(const float4*)(waS + f0 + 4);
        const float4 d0 = *(const float4*)(waD + f0);
        const float4 d1 = *(const float4*)(waD + f0 + 4);
        ws8[0]=s0.x; ws8[1]=s0.y; ws8[2]=s0.z; ws8[3]=s0.w;
        ws8[4]=s1.x; ws8[5]=s1.y; ws8[6]=s1.z; ws8[7]=s1.w;
        wd8[0]=d0.x; wd8[1]=d0.y; wd8[2]=d0.z; wd8[3]=d0.w;
        wd8[4]=d1.x; wd8[5]=d1.y; wd8[6]=d1.z; wd8[7]=d1.w;
    }

    #pragma unroll 1
    for (int i = 0; i < 4; ++i) {
        const int rowIdx = w * 4 + i;
        const int node = rw0 + rowIdx;
        if (node < n) {
            const int start = offs[node];
            const int end   = offs[node + 1];
            const float hdi = hdIn[node];

            float den = 0.f;
            float acc[8] = {};
            if (sub == 0) {   // self-loop
                const float* rp = hp + (((uint)node << 6) + f0);
                const float4 r0 = *(const float4*)rp;
                const float4 r1 = *(const float4*)(rp + 4);
                float e = hsIn[node] + hdi;
                e = (e > 0.f) ? e : NEG_SLOPE * e;
                const float ex = __expf(e);
                den = ex;
                acc[0] = ex * r0.x; acc[1] = ex * r0.y;
                acc[2] = ex * r0.z; acc[3] = ex * r0.w;
                acc[4] = ex * r1.x; acc[5] = ex * r1.y;
                acc[6] = ex * r1.z; acc[7] = ex * r1.w;
            }
            #pragma unroll 2
            for (int j = start + sub; j < end; j += 8) {
                const int s = ssrc[j];
                const float* rp = hp + (((uint)s << 6) + f0);
                const float4 r0 = *(const float4*)rp;
                const float4 r1 = *(const float4*)(rp + 4);
                float e2 = hsIn[s] + hdi;
                e2 = (e2 > 0.f) ? e2 : NEG_SLOPE * e2;
                const float ex2 = __expf(e2);
                den += ex2;
                acc[0] = fmaf(ex2, r0.x, acc[0]); acc[1] = fmaf(ex2, r0.y, acc[1]);
                acc[2] = fmaf(ex2, r0.z, acc[2]); acc[3] = fmaf(ex2, r0.w, acc[3]);
                acc[4] = fmaf(ex2, r1.x, acc[4]); acc[5] = fmaf(ex2, r1.y, acc[5]);
                acc[6] = fmaf(ex2, r1.z, acc[6]); acc[7] = fmaf(ex2, r1.w, acc[7]);
            }
            #pragma unroll
            for (int off = 8; off < 64; off <<= 1) {
                den += __shfl_xor(den, off);
                #pragma unroll
                for (int k = 0; k < 8; ++k) acc[k] += __shfl_xor(acc[k], off);
            }
            const float inv = 1.f / (den + 1e-16f);
            float v[8];
            #pragma unroll
            for (int k = 0; k < 8; ++k)
                v[k] = fmaxf(acc[k] * inv + bb[k], 0.f);
            uint4 o;
            o.x = pk(v[0], v[1]); o.y = pk(v[2], v[3]);
            o.z = pk(v[4], v[5]); o.w = pk(v[6], v[7]);
            // next-layer attn dots from the bf16-rounded a-row
            float rv[8];
            bf2f(o.x, rv[0], rv[1]); bf2f(o.y, rv[2], rv[3]);
            bf2f(o.z, rv[4], rv[5]); bf2f(o.w, rv[6], rv[7]);
            float psum = 0.f, pdum = 0.f;
            #pragma unroll
            for (int k = 0; k < 8; ++k) {
                psum = fmaf(rv[k], ws8[k], psum);
                pdum = fmaf(rv[k], wd8[k], pdum);
            }
            #pragma unroll
            for (int off = 1; off < 8; off <<= 1) {
                psum += __shfl_xor(psum, off);
                pdum += __shfl_xor(pdum, off);
            }
            if (lane == 0) { hsOut[node] = psum; hdOut[node] = pdum; }
            if (sub == 0) *(uint4*)&ldsA[lane & 7][rowIdx][0] = o;
        } else if (sub == 0) {
            const uint4 z = {0u, 0u, 0u, 0u};
            *(uint4*)&ldsA[lane & 7][rowIdx][0] = z;
        }
    }
    __syncthreads();

    // GEMM: wave w -> cols w*16..w*16+15 of h' = a @ W
    const int c = lane & 15, q = lane >> 4;
    const bf16x8 a0 = *(const bf16x8*)&ldsA[q][c][0];
    const bf16x8 a1 = *(const bf16x8*)&ldsA[q + 4][c][0];
    const ushort* bp = WT + (size_t)(w * 16 + c) * 64 + q * 8;
    const bf16x8 b0 = *(const bf16x8*)(bp);
    const bf16x8 b1 = *(const bf16x8*)(bp + 32);
    f32x4 a = (f32x4){0.f, 0.f, 0.f, 0.f};
    a = __builtin_amdgcn_mfma_f32_16x16x32_bf16(a0, b0, a, 0, 0, 0);
    a = __builtin_amdgcn_mfma_f32_16x16x32_bf16(a1, b1, a, 0, 0, 0);
    #pragma unroll
    for (int r = 0; r < 4; ++r)
        ldsC[q * 4 + r][w * 16 + c] = a[r];
    __syncthreads();

    const int row = tid >> 4, co = (tid & 15) * 4;
    if (rw0 + row < n)
        *(float4*)(C + (size_t)(rw0 + row) * 64 + co) = *(const float4*)&ldsC[row][co];
}

// ---------------- final gather aggregation (bias + L2 normalize) -------------
__global__ __launch_bounds__(256) void gat_agg_final(
    const float* __restrict__ hp, const float* __restrict__ hs,
    const float* __restrict__ hd, const int* __restrict__ offs,
    const int* __restrict__ ssrc, const float* __restrict__ bias,
    float* __restrict__ outp, int n)
{
    const int wid  = (blockIdx.x * blockDim.x + threadIdx.x) >> 6;
    const int lane = threadIdx.x & 63;
    if (wid >= n) return;
    const int sub = lane >> 3;
    const int f0  = (lane & 7) * 8;

    const int start = offs[wid];
    const int end   = offs[wid + 1];
    const float hdi = hd[wid];

    float den = 0.f;
    float acc[8] = {};
    if (sub == 0) {
        const float* rp = hp + (((uint)wid << 6) + f0);
        const float4 r0 = *(const float4*)rp;
        const float4 r1 = *(const float4*)(rp + 4);
        float e = hs[wid] + hdi;
        e = (e > 0.f) ? e : NEG_SLOPE * e;
        const float ex = __expf(e);
        den = ex;
        acc[0] = ex * r0.x; acc[1] = ex * r0.y;
        acc[2] = ex * r0.z; acc[3] = ex * r0.w;
        acc[4] = ex * r1.x; acc[5] = ex * r1.y;
        acc[6] = ex * r1.z; acc[7] = ex * r1.w;
    }
    #pragma unroll 2
    for (int j = start + sub; j < end; j += 8) {
        const int s = ssrc[j];
        const float* rp = hp + (((uint)s << 6) + f0);
        const float4 r0 = *(const float4*)rp;
        const float4 r1 = *(const float4*)(rp + 4);
        float e2 = hs[s] + hdi;
        e2 = (e2 > 0.f) ? e2 : NEG_SLOPE * e2;
        const float ex2 = __expf(e2);
        den += ex2;
        acc[0] = fmaf(ex2, r0.x, acc[0]); acc[1] = fmaf(ex2, r0.y, acc[1]);
        acc[2] = fmaf(ex2, r0.z, acc[2]); acc[3] = fmaf(ex2, r0.w, acc[3]);
        acc[4] = fmaf(ex2, r1.x, acc[4]); acc[5] = fmaf(ex2, r1.y, acc[5]);
        acc[6] = fmaf(ex2, r1.z, acc[6]); acc[7] = fmaf(ex2, r1.w, acc[7]);
    }
    #pragma unroll
    for (int off = 8; off < 64; off <<= 1) {
        den += __shfl_xor(den, off);
        #pragma unroll
        for (int i = 0; i < 8; ++i) acc[i] += __shfl_xor(acc[i], off);
    }
    const float4 bv0 = *(const float4*)(bias + f0);
    const float4 bv1 = *(const float4*)(bias + f0 + 4);
    const float bb[8] = {bv0.x, bv0.y, bv0.z, bv0.w, bv1.x, bv1.y, bv1.z, bv1.w};
    const float inv = 1.f / (den + 1e-16f);
    float v[8];
    #pragma unroll
    for (int i = 0; i < 8; ++i) v[i] = acc[i] * inv + bb[i];
    float sq = 0.f;
    #pragma unroll
    for (int i = 0; i < 8; ++i) sq += v[i] * v[i];
    #pragma unroll
    for (int off = 1; off < 8; off <<= 1) sq += __shfl_xor(sq, off);
    const float s = 1.f / fmaxf(sqrtf(sq), 1e-12f);
    if (sub == 0) {
        float* op = outp + (size_t)wid * 64 + f0;
        float4 o0, o1;
        o0.x = v[0] * s; o0.y = v[1] * s; o0.z = v[2] * s; o0.w = v[3] * s;
        o1.x = v[4] * s; o1.y = v[5] * s; o1.z = v[6] * s; o1.w = v[7] * s;
        *(float4*)(op)     = o0;
        *(float4*)(op + 4) = o1;
    }
}

// ---------------- launch -----------------------------------------------------
extern "C" void kernel_launch(void* const* d_in, const int* in_sizes, int n_in,
                              void* d_out, int out_size, void* d_ws, size_t ws_size,
                              hipStream_t stream)
{
    const float* x     = (const float*)d_in[0];
    const int*   src   = (const int*)d_in[1];
    const int*   dst   = (const int*)d_in[2];
    const float* lin_w = (const float*)d_in[3];
    const float* lin_b = (const float*)d_in[4];
    const float* w1  = (const float*)d_in[5];
    const float* a1s = (const float*)d_in[6];
    const float* a1d = (const float*)d_in[7];
    const float* b1  = (const float*)d_in[8];
    const float* w2  = (const float*)d_in[9];
    const float* a2s = (const float*)d_in[10];
    const float* a2d = (const float*)d_in[11];
    const float* b2  = (const float*)d_in[12];
    const float* w3  = (const float*)d_in[13];
    const float* a3s = (const float*)d_in[14];
    const float* a3d = (const float*)d_in[15];
    const float* b3  = (const float*)d_in[16];

    const int n = in_sizes[0] / 256;   // 100000 nodes
    const int E = in_sizes[1];         // 1280000 edges
    const int nb = (n + BKT_N - 1) >> BKT_SHIFT;   // 196 buckets

    char* wsp = (char*)d_ws;
    auto alloc = [&](size_t bytes) -> void* {
        void* p = (void*)wsp;
        wsp += (bytes + 255) & ~(size_t)255;
        return p;
    };
    float*  bufA = (float*)alloc((size_t)n * 64 * sizeof(float));   // fp32 h
    float*  bufB = (float*)alloc((size_t)n * 64 * sizeof(float));   // fp32 h'
    float*  hsA  = (float*)alloc((size_t)n * sizeof(float));
    float*  hdA  = (float*)alloc((size_t)n * sizeof(float));
    float*  hsB  = (float*)alloc((size_t)n * sizeof(float));
    float*  hdB  = (float*)alloc((size_t)n * sizeof(float));
    int*    offs = (int*)alloc((size_t)(n + 1) * sizeof(int));
    int*    cnt  = (int*)alloc((size_t)n * sizeof(int));
    int*    bsum = (int*)alloc(1024 * sizeof(int));
    int*    gcur = (int*)alloc(256 * sizeof(int));
    int*    tick = (int*)alloc(256 * sizeof(int));
    int*    ssrc = (int*)alloc((size_t)E * sizeof(int));
    int*    pairs = (int*)alloc((size_t)E * sizeof(int));
    ushort* lwT = (ushort*)alloc(64 * 256 * sizeof(ushort));
    ushort* w1T = (ushort*)alloc(64 * 64 * sizeof(ushort));
    ushort* w2T = (ushort*)alloc(64 * 64 * sizeof(ushort));
    ushort* w3T = (ushort*)alloc(64 * 64 * sizeof(ushort));
    float*  wvec = (float*)alloc(256 * sizeof(float));  // w2aS,w2aD,w3aS,w3aD

    const int gemmBlocks = (n + 63) / 64;          // 1563 pre_fused tiles
    const int nScanBlocks = (n + 1023) / 1024;     // 98
    const int s3Blocks = (n + 255) / 256;          // 391
    const int histBlocks = (E / 4 + 255) / 256 + 1;
    const int partBlocks = (E + PCHUNK - 1) / PCHUNK;   // 625
    const int fusedBlocks = (n + 15) / 16;         // 6250
    const int aggBlocks = (n + 3) / 4;             // 25000

    const int TA = 200;                            // tiles in scan1
    const int TB = 300;                            // tiles in scan3
    const int TC = 400;                            // tiles in partition
    const int TD = gemmBlocks - TA - TB - TC;      // tiles in bucket scatter

    PreArgs pa{x, lwT, lin_b, w1T, a1s, a1d, bufB, hsB, hdB, n};

    // ---- weight prep + CSR build with folded h0->h'1 tiles ----
    prep_w<<<(n + 255) / 256, 256, 0, stream>>>(
        lin_w, w1, w2, w3, a2s, a2d, a3s, a3d,
        lwT, w1T, w2T, w3T, wvec, cnt, tick, n);
    edge_hist<<<histBlocks, 256, 0, stream>>>(dst, cnt, E);
    scan1_tiles<<<nScanBlocks + TA, 256, 0, stream>>>(
        cnt, offs, bsum, tick, n, nScanBlocks, pa, 0);
    scan3_tiles<<<s3Blocks + TB, 256, 0, stream>>>(
        offs, bsum, gcur, n, E, s3Blocks, pa, TA);
    part_tiles<<<partBlocks + TC, 256, 0, stream>>>(
        src, dst, gcur, pairs, E, nb, partBlocks, pa, TA + TB);
    scat_tiles<<<nb + TD, 256, 0, stream>>>(
        pairs, offs, ssrc, n, nb, pa, TA + TB + TC);

    // ---- layer 1 agg + layer 2 GEMM ----
    fused_ag<<<fusedBlocks, 256, 0, stream>>>(
        bufB, hsB, hdB, offs, ssrc, b1, w2T, wvec, wvec + 64,
        bufA, hsA, hdA, n);
    // ---- layer 2 agg + layer 3 GEMM ----
    fused_ag<<<fusedBlocks, 256, 0, stream>>>(
        bufA, hsA, hdA, offs, ssrc, b2, w3T, wvec + 128, wvec + 192,
        bufB, hsB, hdB, n);
    // ---- layer 3 agg + normalize -> d_out ----
    gat_agg_final<<<aggBlocks, 256, 0, stream>>>(
        bufB, hsB, hdB, offs, ssrc, b3, (float*)d_out, n);
}

// Round 6
// 492.612 us; speedup vs baseline: 1.0243x; 1.0243x over previous
//
#include <hip/hip_runtime.h>

// GAT 3-layer on MI355X — bf16/MFMA pipeline, R11.
//   R10 post-mortem: fp32 rows cut VALU 66->50% but doubled FETCH (72->159MB)
//   and fused_ag regressed 64->75us — the gather is mixed VALU+fetch bound.
//   R11: rows back to bf16 (fetch restored), keep R10's simple loop + 32-bit
//   addressing, plus two fetch-neutral VALU cuts:
//     (a) exp->exp2: hs/hd scaled by log2(e) at production (leaky_relu is
//         positively homogeneous) — gather loop calls exp2f directly.
//     (b) next-layer attn dots from fp32 v[] (no bf16 re-unpack; closer to ref).
//   Structure unchanged: CSR build (hist/scan/partition/bucket-scatter, folded
//   gemm_pre_fused tiles), fused_ag x2, gat_agg_final.

constexpr float NEG_SLOPE = 0.2f;
constexpr float LOG2E = 1.4426950408889634f;
#define BKT_SHIFT 9                // 512 nodes per bucket
#define BKT_N     512
#define PCHUNK    2048             // edges staged per partition block
#define SRC_BITS  17               // N=100000 < 2^17

typedef __attribute__((ext_vector_type(8))) short bf16x8;
typedef __attribute__((ext_vector_type(4))) float f32x4;

__device__ inline ushort f2bf(float x) {
    union { float f; uint u; } v; v.f = x;
    return (ushort)((v.u + 0x7FFFu + ((v.u >> 16) & 1u)) >> 16);
}
__device__ inline void bf2f(uint u, float& lo, float& hi) {
    union { uint u; float f; } a, b;
    a.u = u << 16; b.u = u & 0xFFFF0000u;
    lo = a.f; hi = b.f;
}
__device__ inline uint pk(float a, float b) {
    return (uint)f2bf(a) | ((uint)f2bf(b) << 16);
}

struct PreArgs {
    const float* x; const ushort* lwT; const float* lin_b;
    const ushort* w1T; const float* a1s; const float* a1d;
    ushort* C; float* hs; float* hd; int M;
};

// ---------------- weight prep: bf16 transpose + waS/waD + cnt/ticket zero ----
__global__ __launch_bounds__(256) void prep_w(
    const float* __restrict__ lw, const float* __restrict__ w1,
    const float* __restrict__ w2, const float* __restrict__ w3,
    const float* __restrict__ a2s, const float* __restrict__ a2d,
    const float* __restrict__ a3s, const float* __restrict__ a3d,
    ushort* __restrict__ lwT, ushort* __restrict__ w1T,
    ushort* __restrict__ w2T, ushort* __restrict__ w3T,
    float* __restrict__ wvec,
    int* __restrict__ cnt, int* __restrict__ ticket, int n)
{
    const int i = blockIdx.x * 256 + threadIdx.x;
    if (i < n) cnt[i] = 0;
    if (i == 0) *ticket = 0;
    if (i < 64 * 256) {                 // lwT[n][k] = lw[k][n], K=256
        const int nn = i >> 8, k = i & 255;
        lwT[i] = f2bf(lw[k * 64 + nn]);
    } else if (i < 64 * 256 + 4096) {   // wT[n][k] = w[k][n], K=64
        const int j = i - 64 * 256;
        const int nn = j >> 6, k = j & 63;
        w1T[j] = f2bf(w1[k * 64 + nn]);
        w2T[j] = f2bf(w2[k * 64 + nn]);
        w3T[j] = f2bf(w3[k * 64 + nn]);
    } else if (i < 64 * 256 + 4096 + 256) {
        // wvec[p][k] = LOG2E * sum_n W[k][n]*a[n]; p: 0=w2a2s 1=w2a2d 2=w3a3s 3=w3a3d
        const int j = i - 64 * 256 - 4096;
        const int p = j >> 6, k = j & 63;
        const float* Wp = (p < 2) ? w2 : w3;
        const float* vp = (p == 0) ? a2s : (p == 1) ? a2d : (p == 2) ? a3s : a3d;
        float s = 0.f;
        #pragma unroll
        for (int t = 0; t < 64; ++t) s += Wp[k * 64 + t] * vp[t];
        wvec[p * 64 + k] = s * LOG2E;
    }
}

// ------- gemm_pre_fused tile: h'1 = (x@lw+b)@W1 + attn dots, per 64 rows -----
__device__ __forceinline__ void gemm_pre_fused(const PreArgs& pa, int tile)
{
    __shared__ __align__(16) ushort ldsA[4][8][16][8];   // [wave][kblk][row][8]
    __shared__ __align__(16) ushort ctile[4][16][64];
    const int tid = threadIdx.x;
    const int w = tid >> 6, lane = tid & 63;
    const int rw0 = (tile * 4 + w) * 16;
    if (rw0 >= pa.M) return;
    const int c = lane & 15, q = lane >> 4;

    // ---- stage 1: h0 = x @ lin_w (+ lin_b) ----
    const float* ap = pa.x + (size_t)(rw0 + c) * 256 + q * 8;
    float4 pv[16];
    #pragma unroll
    for (int s = 0; s < 8; ++s) {
        pv[2 * s]     = *(const float4*)(ap + s * 32);
        pv[2 * s + 1] = *(const float4*)(ap + s * 32 + 4);
    }
    f32x4 acc[4];
    #pragma unroll
    for (int t = 0; t < 4; ++t) acc[t] = (f32x4){0.f, 0.f, 0.f, 0.f};
    #pragma unroll
    for (int s = 0; s < 8; ++s) {
        const float4 p0 = pv[2 * s];
        const float4 p1 = pv[2 * s + 1];
        bf16x8 af;
        af[0] = (short)f2bf(p0.x); af[1] = (short)f2bf(p0.y);
        af[2] = (short)f2bf(p0.z); af[3] = (short)f2bf(p0.w);
        af[4] = (short)f2bf(p1.x); af[5] = (short)f2bf(p1.y);
        af[6] = (short)f2bf(p1.z); af[7] = (short)f2bf(p1.w);
        #pragma unroll
        for (int t = 0; t < 4; ++t) {
            const bf16x8 bf = *(const bf16x8*)(pa.lwT + (size_t)(t * 16 + c) * 256 + s * 32 + q * 8);
            acc[t] = __builtin_amdgcn_mfma_f32_16x16x32_bf16(af, bf, acc[t], 0, 0, 0);
        }
    }
    // round h0+bias into fragment-layout LDS (row=q*4+r, col=16t+c)
    #pragma unroll
    for (int t = 0; t < 4; ++t) {
        const float bv = pa.lin_b[t * 16 + c];
        const int kb = 2 * t + (c >> 3);
        const int e  = c & 7;
        #pragma unroll
        for (int r = 0; r < 4; ++r)
            ldsA[w][kb][q * 4 + r][e] = f2bf(acc[t][r] + bv);
    }

    // ---- stage 2: h'1 = h0 @ W1 (+ dots) ----  (same-wave LDS RAW: DS in-order)
    const bf16x8 a0 = *(const bf16x8*)&ldsA[w][q][c][0];
    const bf16x8 a1 = *(const bf16x8*)&ldsA[w][q + 4][c][0];
    f32x4 acc2[4];
    #pragma unroll
    for (int t = 0; t < 4; ++t) {
        const ushort* bp = pa.w1T + (size_t)(t * 16 + c) * 64 + q * 8;
        const bf16x8 b0 = *(const bf16x8*)(bp);
        const bf16x8 b1 = *(const bf16x8*)(bp + 32);
        f32x4 a = (f32x4){0.f, 0.f, 0.f, 0.f};
        a = __builtin_amdgcn_mfma_f32_16x16x32_bf16(a0, b0, a, 0, 0, 0);
        a = __builtin_amdgcn_mfma_f32_16x16x32_bf16(a1, b1, a, 0, 0, 0);
        acc2[t] = a;
    }
    // attn dots (scaled by LOG2E for exp2 in the gather)
    float ps[4] = {0.f, 0.f, 0.f, 0.f}, pd[4] = {0.f, 0.f, 0.f, 0.f};
    #pragma unroll
    for (int t = 0; t < 4; ++t) {
        const float as = pa.a1s[t * 16 + c], ad = pa.a1d[t * 16 + c];
        #pragma unroll
        for (int r = 0; r < 4; ++r) {
            ps[r] = fmaf(acc2[t][r], as, ps[r]);
            pd[r] = fmaf(acc2[t][r], ad, pd[r]);
        }
    }
    #pragma unroll
    for (int r = 0; r < 4; ++r) {
        #pragma unroll
        for (int off = 1; off < 16; off <<= 1) {
            ps[r] += __shfl_xor(ps[r], off);
            pd[r] += __shfl_xor(pd[r], off);
        }
    }
    if (c == 0) {
        #pragma unroll
        for (int r = 0; r < 4; ++r) {
            pa.hs[rw0 + q * 4 + r] = ps[r] * LOG2E;
            pa.hd[rw0 + q * 4 + r] = pd[r] * LOG2E;
        }
    }
    // bf16 store via per-wave LDS transpose
    #pragma unroll
    for (int t = 0; t < 4; ++t)
        #pragma unroll
        for (int r = 0; r < 4; ++r)
            ctile[w][q * 4 + r][t * 16 + c] = f2bf(acc2[t][r]);
    const int row = lane >> 2, eo = (lane & 3) * 16;
    const uint4 v0 = *(const uint4*)(&ctile[w][row][eo]);
    const uint4 v1 = *(const uint4*)(&ctile[w][row][eo + 8]);
    *(uint4*)(pa.C + (size_t)(rw0 + row) * 64 + eo)     = v0;
    *(uint4*)(pa.C + (size_t)(rw0 + row) * 64 + eo + 8) = v1;
}

// ---------------- CSR build --------------------------------------------------
__global__ __launch_bounds__(256) void edge_hist(
    const int* __restrict__ dst, int* __restrict__ cnt, int e)
{
    const int i0 = (blockIdx.x * 256 + threadIdx.x) * 4;
    if (i0 + 3 < e) {
        const int4 d = *(const int4*)(dst + i0);
        atomicAdd(&cnt[d.x], 1); atomicAdd(&cnt[d.y], 1);
        atomicAdd(&cnt[d.z], 1); atomicAdd(&cnt[d.w], 1);
    } else {
        for (int k = i0; k < e; ++k) atomicAdd(&cnt[dst[k]], 1);
    }
}

__global__ __launch_bounds__(256) void scan1_tiles(
    const int* __restrict__ cnt, int* __restrict__ out,
    int* __restrict__ bsum, int* __restrict__ ticket, int n, int nblk,
    PreArgs pa, int tile0)
{
    __shared__ int wsum[4];
    __shared__ int amLastS;
    if ((int)blockIdx.x >= nblk) {
        gemm_pre_fused(pa, tile0 + (int)blockIdx.x - nblk);
        return;
    }
    const int tid  = threadIdx.x;
    const int lane = tid & 63;
    const int w    = tid >> 6;
    const int base = blockIdx.x * 1024;
    int vals[4];
    int tsum = 0;
    #pragma unroll
    for (int i = 0; i < 4; ++i) {
        const int idx = base + tid * 4 + i;
        vals[i] = (idx < n) ? cnt[idx] : 0;
        tsum += vals[i];
    }
    int x1 = tsum;
    #pragma unroll
    for (int off = 1; off < 64; off <<= 1) {
        const int y = __shfl_up(x1, off);
        if (lane >= off) x1 += y;
    }
    if (lane == 63) wsum[w] = x1;
    __syncthreads();
    int wofs = 0;
    for (int k = 0; k < w; ++k) wofs += wsum[k];
    int excl = wofs + x1 - tsum;
    #pragma unroll
    for (int i = 0; i < 4; ++i) {
        const int idx = base + tid * 4 + i;
        if (idx < n) out[idx] = excl;
        excl += vals[i];
    }
    if (tid == 255) {
        bsum[blockIdx.x] = wofs + x1;
        __threadfence();                       // release bsum write
        amLastS = (atomicAdd(ticket, 1) == nblk - 1) ? 1 : 0;
    }
    __syncthreads();
    if (amLastS) {                             // last block scans bsum[nblk]
        __threadfence();                       // acquire others' bsum writes
        const int v2 = (tid < nblk) ? bsum[tid] : 0;
        int x2 = v2;
        #pragma unroll
        for (int off = 1; off < 64; off <<= 1) {
            const int y = __shfl_up(x2, off);
            if (lane >= off) x2 += y;
        }
        if (lane == 63) wsum[w] = x2;
        __syncthreads();
        int c2 = 0;
        for (int k = 0; k < w; ++k) c2 += wsum[k];
        if (tid < nblk) bsum[tid] = c2 + x2 - v2;
    }
}

__global__ __launch_bounds__(256) void scan3_tiles(
    int* __restrict__ out, const int* __restrict__ bsum,
    int* __restrict__ gcur, int n, int total, int s3b,
    PreArgs pa, int tile0)
{
    if ((int)blockIdx.x >= s3b) {
        gemm_pre_fused(pa, tile0 + (int)blockIdx.x - s3b);
        return;
    }
    const int idx = blockIdx.x * 256 + threadIdx.x;
    if (idx < n) {
        const int v = out[idx] + bsum[idx >> 10];
        out[idx] = v;
        if ((idx & (BKT_N - 1)) == 0) gcur[idx >> BKT_SHIFT] = v;
    }
    if (idx == 0) out[n] = total;
}

__global__ __launch_bounds__(256) void part_tiles(
    const int* __restrict__ src, const int* __restrict__ dst,
    int* __restrict__ gcursor, int* __restrict__ pairs, int e, int nb, int pb,
    PreArgs pa, int tile0)
{
    __shared__ int stage[PCHUNK];
    __shared__ unsigned char sbkt[PCHUNK];
    __shared__ int lcnt[256];
    __shared__ int lstart[256];
    __shared__ int lfill[256];
    __shared__ int gbase[256];
    __shared__ int wsum[4];

    if ((int)blockIdx.x >= pb) {
        gemm_pre_fused(pa, tile0 + (int)blockIdx.x - pb);
        return;
    }

    const int tid  = threadIdx.x;
    const int lane = tid & 63;
    const int w    = tid >> 6;
    const int base = blockIdx.x * PCHUNK;
    const int cnt_here = min(PCHUNK, e - base);

    lcnt[tid] = 0; lfill[tid] = 0;
    __syncthreads();

    for (int i = tid; i < cnt_here; i += 256)
        atomicAdd(&lcnt[dst[base + i] >> BKT_SHIFT], 1);
    __syncthreads();

    const int v = lcnt[tid];
    int x1 = v;
    #pragma unroll
    for (int off = 1; off < 64; off <<= 1) {
        const int y = __shfl_up(x1, off);
        if (lane >= off) x1 += y;
    }
    if (lane == 63) wsum[w] = x1;
    __syncthreads();
    int carry = 0;
    for (int k = 0; k < w; ++k) carry += wsum[k];
    lstart[tid] = carry + x1 - v;
    if (tid < nb && v > 0) gbase[tid] = atomicAdd(&gcursor[tid], v);
    __syncthreads();

    for (int i = tid; i < cnt_here; i += 256) {
        const int d = dst[base + i];
        const int s = src[base + i];
        const int b = d >> BKT_SHIFT;
        const int p = lstart[b] + atomicAdd(&lfill[b], 1);
        stage[p] = ((d & (BKT_N - 1)) << SRC_BITS) | s;
        sbkt[p]  = (unsigned char)b;
    }
    __syncthreads();

    for (int t = tid; t < cnt_here; t += 256) {
        const int b = sbkt[t];
        pairs[gbase[b] + (t - lstart[b])] = stage[t];
    }
}

__global__ __launch_bounds__(256) void scat_tiles(
    const int* __restrict__ pairs, const int* __restrict__ offs,
    int* __restrict__ ssrc, int n, int sb,
    PreArgs pa, int tile0)
{
    __shared__ int pos[BKT_N];
    if ((int)blockIdx.x >= sb) {
        gemm_pre_fused(pa, tile0 + (int)blockIdx.x - sb);
        return;
    }
    const int node0 = blockIdx.x << BKT_SHIFT;
    const int node1 = min(n, node0 + BKT_N);
    const int tid = threadIdx.x;
    for (int i = tid; i < node1 - node0; i += 256) pos[i] = offs[node0 + i];
    __syncthreads();
    const int e0 = offs[node0];
    const int e1 = offs[node1];
    for (int j = e0 + tid; j < e1; j += 256) {
        const int pr = pairs[j];
        const int p = atomicAdd(&pos[pr >> SRC_BITS], 1);
        ssrc[p] = pr & ((1 << SRC_BITS) - 1);
    }
}

// -------- fused aggregate + next-layer GEMM ----------------------------------
// Block = 16 nodes (4 waves x 4 nodes). bf16 rows (fetch-lean), simple loop,
// 32-bit addressing, exp2-form logits (hs/hd pre-scaled by log2e).
__global__ __launch_bounds__(256) void fused_ag(
    const ushort* __restrict__ hp, const float* __restrict__ hsIn,
    const float* __restrict__ hdIn, const int* __restrict__ offs,
    const int* __restrict__ ssrc, const float* __restrict__ bias,
    const ushort* __restrict__ WT, const float* __restrict__ waS,
    const float* __restrict__ waD,
    ushort* __restrict__ C, float* __restrict__ hsOut, float* __restrict__ hdOut,
    int n)
{
    __shared__ __align__(16) ushort ldsA[8][16][8];   // [kblk][row][8] bf16
    __shared__ __align__(16) ushort ldsC[16][68];
    const int tid  = threadIdx.x;
    const int w    = tid >> 6, lane = tid & 63;
    const int rw0  = blockIdx.x * 16;
    const int sub  = lane >> 3;
    const int f0   = (lane & 7) * 8;

    const float4 bv0 = *(const float4*)(bias + f0);
    const float4 bv1 = *(const float4*)(bias + f0 + 4);
    const float bb[8] = {bv0.x, bv0.y, bv0.z, bv0.w, bv1.x, bv1.y, bv1.z, bv1.w};
    float ws8[8], wd8[8];
    {
        const float4 s0 = *(const float4*)(waS + f0);
        const float4 s1 = *(const float4*)(waS + f0 + 4);
        const float4 d0 = *(const float4*)(waD + f0);
        const float4 d1 = *(const float4*)(waD + f0 + 4);
        ws8[0]=s0.x; ws8[1]=s0.y; ws8[2]=s0.z; ws8[3]=s0.w;
        ws8[4]=s1.x; ws8[5]=s1.y; ws8[6]=s1.z; ws8[7]=s1.w;
        wd8[0]=d0.x; wd8[1]=d0.y; wd8[2]=d0.z; wd8[3]=d0.w;
        wd8[4]=d1.x; wd8[5]=d1.y; wd8[6]=d1.z; wd8[7]=d1.w;
    }

    #pragma unroll 1
    for (int i = 0; i < 4; ++i) {
        const int rowIdx = w * 4 + i;
        const int node = rw0 + rowIdx;
        if (node < n) {
            const int start = offs[node];
            const int end   = offs[node + 1];
            const float hdi = hdIn[node];

            float den = 0.f;
            float acc[8] = {};
            if (sub == 0) {   // self-loop
                const uint4 t = *(const uint4*)(hp + (((uint)node << 6) + f0));
                float e = hsIn[node] + hdi;
                e = (e > 0.f) ? e : NEG_SLOPE * e;
                const float ex = exp2f(e);
                float f[8];
                bf2f(t.x, f[0], f[1]); bf2f(t.y, f[2], f[3]);
                bf2f(t.z, f[4], f[5]); bf2f(t.w, f[6], f[7]);
                den = ex;
                #pragma unroll
                for (int k = 0; k < 8; ++k) acc[k] = ex * f[k];
            }
            #pragma unroll 2
            for (int j = start + sub; j < end; j += 8) {
                const int s = ssrc[j];
                const uint4 t = *(const uint4*)(hp + (((uint)s << 6) + f0));
                float e2 = hsIn[s] + hdi;
                e2 = (e2 > 0.f) ? e2 : NEG_SLOPE * e2;
                const float ex2 = exp2f(e2);
                float f[8];
                bf2f(t.x, f[0], f[1]); bf2f(t.y, f[2], f[3]);
                bf2f(t.z, f[4], f[5]); bf2f(t.w, f[6], f[7]);
                den += ex2;
                #pragma unroll
                for (int k = 0; k < 8; ++k) acc[k] = fmaf(ex2, f[k], acc[k]);
            }
            #pragma unroll
            for (int off = 8; off < 64; off <<= 1) {
                den += __shfl_xor(den, off);
                #pragma unroll
                for (int k = 0; k < 8; ++k) acc[k] += __shfl_xor(acc[k], off);
            }
            const float inv = 1.f / (den + 1e-16f);
            float v[8];
            #pragma unroll
            for (int k = 0; k < 8; ++k)
                v[k] = fmaxf(acc[k] * inv + bb[k], 0.f);
            // next-layer attn dots from fp32 v (closer to ref than bf16-rounded)
            float psum = 0.f, pdum = 0.f;
            #pragma unroll
            for (int k = 0; k < 8; ++k) {
                psum = fmaf(v[k], ws8[k], psum);
                pdum = fmaf(v[k], wd8[k], pdum);
            }
            #pragma unroll
            for (int off = 1; off < 8; off <<= 1) {
                psum += __shfl_xor(psum, off);
                pdum += __shfl_xor(pdum, off);
            }
            if (lane == 0) { hsOut[node] = psum; hdOut[node] = pdum; }
            if (sub == 0) {
                uint4 o;
                o.x = pk(v[0], v[1]); o.y = pk(v[2], v[3]);
                o.z = pk(v[4], v[5]); o.w = pk(v[6], v[7]);
                *(uint4*)&ldsA[lane & 7][rowIdx][0] = o;
            }
        } else if (sub == 0) {
            const uint4 z = {0u, 0u, 0u, 0u};
            *(uint4*)&ldsA[lane & 7][rowIdx][0] = z;
        }
    }
    __syncthreads();

    // GEMM: wave w -> cols w*16..w*16+15 of h' = a @ W
    const int c = lane & 15, q = lane >> 4;
    const bf16x8 a0 = *(const bf16x8*)&ldsA[q][c][0];
    const bf16x8 a1 = *(const bf16x8*)&ldsA[q + 4][c][0];
    const ushort* bp = WT + (size_t)(w * 16 + c) * 64 + q * 8;
    const bf16x8 b0 = *(const bf16x8*)(bp);
    const bf16x8 b1 = *(const bf16x8*)(bp + 32);
    f32x4 a = (f32x4){0.f, 0.f, 0.f, 0.f};
    a = __builtin_amdgcn_mfma_f32_16x16x32_bf16(a0, b0, a, 0, 0, 0);
    a = __builtin_amdgcn_mfma_f32_16x16x32_bf16(a1, b1, a, 0, 0, 0);
    #pragma unroll
    for (int r = 0; r < 4; ++r)
        ldsC[q * 4 + r][w * 16 + c] = f2bf(a[r]);
    __syncthreads();

    const int row = tid >> 4, co = (tid & 15) * 4;
    if (rw0 + row < n)
        *(uint2*)(C + (size_t)(rw0 + row) * 64 + co) = *(const uint2*)&ldsC[row][co];
}

// ---------------- final gather aggregation (bias + L2 normalize) -------------
__global__ __launch_bounds__(256) void gat_agg_final(
    const ushort* __restrict__ hp, const float* __restrict__ hs,
    const float* __restrict__ hd, const int* __restrict__ offs,
    const int* __restrict__ ssrc, const float* __restrict__ bias,
    float* __restrict__ outp, int n)
{
    const int wid  = (blockIdx.x * blockDim.x + threadIdx.x) >> 6;
    const int lane = threadIdx.x & 63;
    if (wid >= n) return;
    const int sub = lane >> 3;
    const int f0  = (lane & 7) * 8;

    const int start = offs[wid];
    const int end   = offs[wid + 1];
    const float hdi = hd[wid];

    float den = 0.f;
    float acc[8] = {};
    if (sub == 0) {
        const uint4 t = *(const uint4*)(hp + (((uint)wid << 6) + f0));
        float e = hs[wid] + hdi;
        e = (e > 0.f) ? e : NEG_SLOPE * e;
        const float ex = exp2f(e);
        float f[8];
        bf2f(t.x, f[0], f[1]); bf2f(t.y, f[2], f[3]);
        bf2f(t.z, f[4], f[5]); bf2f(t.w, f[6], f[7]);
        den = ex;
        #pragma unroll
        for (int i = 0; i < 8; ++i) acc[i] = ex * f[i];
    }
    #pragma unroll 2
    for (int j = start + sub; j < end; j += 8) {
        const int s = ssrc[j];
        const uint4 t = *(const uint4*)(hp + (((uint)s << 6) + f0));
        float e2 = hs[s] + hdi;
        e2 = (e2 > 0.f) ? e2 : NEG_SLOPE * e2;
        const float ex2 = exp2f(e2);
        float f[8];
        bf2f(t.x, f[0], f[1]); bf2f(t.y, f[2], f[3]);
        bf2f(t.z, f[4], f[5]); bf2f(t.w, f[6], f[7]);
        den += ex2;
        #pragma unroll
        for (int i = 0; i < 8; ++i) acc[i] = fmaf(ex2, f[i], acc[i]);
    }
    #pragma unroll
    for (int off = 8; off < 64; off <<= 1) {
        den += __shfl_xor(den, off);
        #pragma unroll
        for (int i = 0; i < 8; ++i) acc[i] += __shfl_xor(acc[i], off);
    }
    const float4 bv0 = *(const float4*)(bias + f0);
    const float4 bv1 = *(const float4*)(bias + f0 + 4);
    const float bb[8] = {bv0.x, bv0.y, bv0.z, bv0.w, bv1.x, bv1.y, bv1.z, bv1.w};
    const float inv = 1.f / (den + 1e-16f);
    float v[8];
    #pragma unroll
    for (int i = 0; i < 8; ++i) v[i] = acc[i] * inv + bb[i];
    float sq = 0.f;
    #pragma unroll
    for (int i = 0; i < 8; ++i) sq += v[i] * v[i];
    #pragma unroll
    for (int off = 1; off < 8; off <<= 1) sq += __shfl_xor(sq, off);
    const float s = 1.f / fmaxf(sqrtf(sq), 1e-12f);
    if (sub == 0) {
        float* op = outp + (size_t)wid * 64 + f0;
        float4 o0, o1;
        o0.x = v[0] * s; o0.y = v[1] * s; o0.z = v[2] * s; o0.w = v[3] * s;
        o1.x = v[4] * s; o1.y = v[5] * s; o1.z = v[6] * s; o1.w = v[7] * s;
        *(float4*)(op)     = o0;
        *(float4*)(op + 4) = o1;
    }
}

// ---------------- launch -----------------------------------------------------
extern "C" void kernel_launch(void* const* d_in, const int* in_sizes, int n_in,
                              void* d_out, int out_size, void* d_ws, size_t ws_size,
                              hipStream_t stream)
{
    const float* x     = (const float*)d_in[0];
    const int*   src   = (const int*)d_in[1];
    const int*   dst   = (const int*)d_in[2];
    const float* lin_w = (const float*)d_in[3];
    const float* lin_b = (const float*)d_in[4];
    const float* w1  = (const float*)d_in[5];
    const float* a1s = (const float*)d_in[6];
    const float* a1d = (const float*)d_in[7];
    const float* b1  = (const float*)d_in[8];
    const float* w2  = (const float*)d_in[9];
    const float* a2s = (const float*)d_in[10];
    const float* a2d = (const float*)d_in[11];
    const float* b2  = (const float*)d_in[12];
    const float* w3  = (const float*)d_in[13];
    const float* a3s = (const float*)d_in[14];
    const float* a3d = (const float*)d_in[15];
    const float* b3  = (const float*)d_in[16];

    const int n = in_sizes[0] / 256;   // 100000 nodes
    const int E = in_sizes[1];         // 1280000 edges
    const int nb = (n + BKT_N - 1) >> BKT_SHIFT;   // 196 buckets

    char* wsp = (char*)d_ws;
    auto alloc = [&](size_t bytes) -> void* {
        void* p = (void*)wsp;
        wsp += (bytes + 255) & ~(size_t)255;
        return p;
    };
    ushort* bufA = (ushort*)alloc((size_t)n * 64 * sizeof(ushort));  // bf16 h
    ushort* bufB = (ushort*)alloc((size_t)n * 64 * sizeof(ushort));  // bf16 h'
    float*  hsA  = (float*)alloc((size_t)n * sizeof(float));
    float*  hdA  = (float*)alloc((size_t)n * sizeof(float));
    float*  hsB  = (float*)alloc((size_t)n * sizeof(float));
    float*  hdB  = (float*)alloc((size_t)n * sizeof(float));
    int*    offs = (int*)alloc((size_t)(n + 1) * sizeof(int));
    int*    cnt  = (int*)alloc((size_t)n * sizeof(int));
    int*    bsum = (int*)alloc(1024 * sizeof(int));
    int*    gcur = (int*)alloc(256 * sizeof(int));
    int*    tick = (int*)alloc(256 * sizeof(int));
    int*    ssrc = (int*)alloc((size_t)E * sizeof(int));
    int*    pairs = (int*)alloc((size_t)E * sizeof(int));
    ushort* lwT = (ushort*)alloc(64 * 256 * sizeof(ushort));
    ushort* w1T = (ushort*)alloc(64 * 64 * sizeof(ushort));
    ushort* w2T = (ushort*)alloc(64 * 64 * sizeof(ushort));
    ushort* w3T = (ushort*)alloc(64 * 64 * sizeof(ushort));
    float*  wvec = (float*)alloc(256 * sizeof(float));  // w2aS,w2aD,w3aS,w3aD (x LOG2E)

    const int gemmBlocks = (n + 63) / 64;          // 1563 pre_fused tiles
    const int nScanBlocks = (n + 1023) / 1024;     // 98
    const int s3Blocks = (n + 255) / 256;          // 391
    const int histBlocks = (E / 4 + 255) / 256 + 1;
    const int partBlocks = (E + PCHUNK - 1) / PCHUNK;   // 625
    const int fusedBlocks = (n + 15) / 16;         // 6250
    const int aggBlocks = (n + 3) / 4;             // 25000

    const int TA = 200;                            // tiles in scan1
    const int TB = 300;                            // tiles in scan3
    const int TC = 400;                            // tiles in partition
    const int TD = gemmBlocks - TA - TB - TC;      // tiles in bucket scatter

    PreArgs pa{x, lwT, lin_b, w1T, a1s, a1d, bufB, hsB, hdB, n};

    // ---- weight prep + CSR build with folded h0->h'1 tiles ----
    prep_w<<<(n + 255) / 256, 256, 0, stream>>>(
        lin_w, w1, w2, w3, a2s, a2d, a3s, a3d,
        lwT, w1T, w2T, w3T, wvec, cnt, tick, n);
    edge_hist<<<histBlocks, 256, 0, stream>>>(dst, cnt, E);
    scan1_tiles<<<nScanBlocks + TA, 256, 0, stream>>>(
        cnt, offs, bsum, tick, n, nScanBlocks, pa, 0);
    scan3_tiles<<<s3Blocks + TB, 256, 0, stream>>>(
        offs, bsum, gcur, n, E, s3Blocks, pa, TA);
    part_tiles<<<partBlocks + TC, 256, 0, stream>>>(
        src, dst, gcur, pairs, E, nb, partBlocks, pa, TA + TB);
    scat_tiles<<<nb + TD, 256, 0, stream>>>(
        pairs, offs, ssrc, n, nb, pa, TA + TB + TC);

    // ---- layer 1 agg + layer 2 GEMM ----
    fused_ag<<<fusedBlocks, 256, 0, stream>>>(
        bufB, hsB, hdB, offs, ssrc, b1, w2T, wvec, wvec + 64,
        bufA, hsA, hdA, n);
    // ---- layer 2 agg + layer 3 GEMM ----
    fused_ag<<<fusedBlocks, 256, 0, stream>>>(
        bufA, hsA, hdA, offs, ssrc, b2, w3T, wvec + 128, wvec + 192,
        bufB, hsB, hdB, n);
    // ---- layer 3 agg + normalize -> d_out ----
    gat_agg_final<<<aggBlocks, 256, 0, stream>>>(
        bufB, hsB, hdB, offs, ssrc, b3, (float*)d_out, n);
}

// Round 7
// 472.266 us; speedup vs baseline: 1.0685x; 1.0431x over previous
//
#include <hip/hip_runtime.h>

// GAT 3-layer on MI355X — bf16/MFMA pipeline, R12.
//   R11 post-mortem: deleting the gather software pipeline regressed fused_ag
//   64->72.6us at identical FETCH and LOWER VALUBusy — the gather is partially
//   latency-bound; R6's "pipeline is null" was structure-specific and did NOT
//   transfer to fused_ag. R12 = measured-best merge:
//     R9's 2-deep-index / 1-deep-data software pipeline   (latency cover)
//   + R11's exp2-form logits (hs/hd pre-scaled by log2e)  (1 v_mul/edge saved)
//   + R11's attn dots from fp32 v[]                        (8 bf2f/node saved)
//   + 32-bit gather addressing.
//   Everything else unchanged: CSR build (hist/scan/partition/bucket-scatter
//   with folded gemm_pre_fused tiles), fused_ag x2, gat_agg_final.

constexpr float NEG_SLOPE = 0.2f;
constexpr float LOG2E = 1.4426950408889634f;
#define BKT_SHIFT 9                // 512 nodes per bucket
#define BKT_N     512
#define PCHUNK    2048             // edges staged per partition block
#define SRC_BITS  17               // N=100000 < 2^17

typedef __attribute__((ext_vector_type(8))) short bf16x8;
typedef __attribute__((ext_vector_type(4))) float f32x4;

__device__ inline ushort f2bf(float x) {
    union { float f; uint u; } v; v.f = x;
    return (ushort)((v.u + 0x7FFFu + ((v.u >> 16) & 1u)) >> 16);
}
__device__ inline void bf2f(uint u, float& lo, float& hi) {
    union { uint u; float f; } a, b;
    a.u = u << 16; b.u = u & 0xFFFF0000u;
    lo = a.f; hi = b.f;
}
__device__ inline uint pk(float a, float b) {
    return (uint)f2bf(a) | ((uint)f2bf(b) << 16);
}

struct PreArgs {
    const float* x; const ushort* lwT; const float* lin_b;
    const ushort* w1T; const float* a1s; const float* a1d;
    ushort* C; float* hs; float* hd; int M;
};

// ---------------- weight prep: bf16 transpose + waS/waD + cnt/ticket zero ----
__global__ __launch_bounds__(256) void prep_w(
    const float* __restrict__ lw, const float* __restrict__ w1,
    const float* __restrict__ w2, const float* __restrict__ w3,
    const float* __restrict__ a2s, const float* __restrict__ a2d,
    const float* __restrict__ a3s, const float* __restrict__ a3d,
    ushort* __restrict__ lwT, ushort* __restrict__ w1T,
    ushort* __restrict__ w2T, ushort* __restrict__ w3T,
    float* __restrict__ wvec,
    int* __restrict__ cnt, int* __restrict__ ticket, int n)
{
    const int i = blockIdx.x * 256 + threadIdx.x;
    if (i < n) cnt[i] = 0;
    if (i == 0) *ticket = 0;
    if (i < 64 * 256) {                 // lwT[n][k] = lw[k][n], K=256
        const int nn = i >> 8, k = i & 255;
        lwT[i] = f2bf(lw[k * 64 + nn]);
    } else if (i < 64 * 256 + 4096) {   // wT[n][k] = w[k][n], K=64
        const int j = i - 64 * 256;
        const int nn = j >> 6, k = j & 63;
        w1T[j] = f2bf(w1[k * 64 + nn]);
        w2T[j] = f2bf(w2[k * 64 + nn]);
        w3T[j] = f2bf(w3[k * 64 + nn]);
    } else if (i < 64 * 256 + 4096 + 256) {
        // wvec[p][k] = LOG2E * sum_n W[k][n]*a[n]; p: 0=w2a2s 1=w2a2d 2=w3a3s 3=w3a3d
        const int j = i - 64 * 256 - 4096;
        const int p = j >> 6, k = j & 63;
        const float* Wp = (p < 2) ? w2 : w3;
        const float* vp = (p == 0) ? a2s : (p == 1) ? a2d : (p == 2) ? a3s : a3d;
        float s = 0.f;
        #pragma unroll
        for (int t = 0; t < 64; ++t) s += Wp[k * 64 + t] * vp[t];
        wvec[p * 64 + k] = s * LOG2E;
    }
}

// ------- gemm_pre_fused tile: h'1 = (x@lw+b)@W1 + attn dots, per 64 rows -----
__device__ __forceinline__ void gemm_pre_fused(const PreArgs& pa, int tile)
{
    __shared__ __align__(16) ushort ldsA[4][8][16][8];   // [wave][kblk][row][8]
    __shared__ __align__(16) ushort ctile[4][16][64];
    const int tid = threadIdx.x;
    const int w = tid >> 6, lane = tid & 63;
    const int rw0 = (tile * 4 + w) * 16;
    if (rw0 >= pa.M) return;
    const int c = lane & 15, q = lane >> 4;

    // ---- stage 1: h0 = x @ lin_w (+ lin_b) ----
    const float* ap = pa.x + (size_t)(rw0 + c) * 256 + q * 8;
    float4 pv[16];
    #pragma unroll
    for (int s = 0; s < 8; ++s) {
        pv[2 * s]     = *(const float4*)(ap + s * 32);
        pv[2 * s + 1] = *(const float4*)(ap + s * 32 + 4);
    }
    f32x4 acc[4];
    #pragma unroll
    for (int t = 0; t < 4; ++t) acc[t] = (f32x4){0.f, 0.f, 0.f, 0.f};
    #pragma unroll
    for (int s = 0; s < 8; ++s) {
        const float4 p0 = pv[2 * s];
        const float4 p1 = pv[2 * s + 1];
        bf16x8 af;
        af[0] = (short)f2bf(p0.x); af[1] = (short)f2bf(p0.y);
        af[2] = (short)f2bf(p0.z); af[3] = (short)f2bf(p0.w);
        af[4] = (short)f2bf(p1.x); af[5] = (short)f2bf(p1.y);
        af[6] = (short)f2bf(p1.z); af[7] = (short)f2bf(p1.w);
        #pragma unroll
        for (int t = 0; t < 4; ++t) {
            const bf16x8 bf = *(const bf16x8*)(pa.lwT + (size_t)(t * 16 + c) * 256 + s * 32 + q * 8);
            acc[t] = __builtin_amdgcn_mfma_f32_16x16x32_bf16(af, bf, acc[t], 0, 0, 0);
        }
    }
    // round h0+bias into fragment-layout LDS (row=q*4+r, col=16t+c)
    #pragma unroll
    for (int t = 0; t < 4; ++t) {
        const float bv = pa.lin_b[t * 16 + c];
        const int kb = 2 * t + (c >> 3);
        const int e  = c & 7;
        #pragma unroll
        for (int r = 0; r < 4; ++r)
            ldsA[w][kb][q * 4 + r][e] = f2bf(acc[t][r] + bv);
    }

    // ---- stage 2: h'1 = h0 @ W1 (+ dots) ----  (same-wave LDS RAW: DS in-order)
    const bf16x8 a0 = *(const bf16x8*)&ldsA[w][q][c][0];
    const bf16x8 a1 = *(const bf16x8*)&ldsA[w][q + 4][c][0];
    f32x4 acc2[4];
    #pragma unroll
    for (int t = 0; t < 4; ++t) {
        const ushort* bp = pa.w1T + (size_t)(t * 16 + c) * 64 + q * 8;
        const bf16x8 b0 = *(const bf16x8*)(bp);
        const bf16x8 b1 = *(const bf16x8*)(bp + 32);
        f32x4 a = (f32x4){0.f, 0.f, 0.f, 0.f};
        a = __builtin_amdgcn_mfma_f32_16x16x32_bf16(a0, b0, a, 0, 0, 0);
        a = __builtin_amdgcn_mfma_f32_16x16x32_bf16(a1, b1, a, 0, 0, 0);
        acc2[t] = a;
    }
    // attn dots (scaled by LOG2E for exp2 in the gather)
    float ps[4] = {0.f, 0.f, 0.f, 0.f}, pd[4] = {0.f, 0.f, 0.f, 0.f};
    #pragma unroll
    for (int t = 0; t < 4; ++t) {
        const float as = pa.a1s[t * 16 + c], ad = pa.a1d[t * 16 + c];
        #pragma unroll
        for (int r = 0; r < 4; ++r) {
            ps[r] = fmaf(acc2[t][r], as, ps[r]);
            pd[r] = fmaf(acc2[t][r], ad, pd[r]);
        }
    }
    #pragma unroll
    for (int r = 0; r < 4; ++r) {
        #pragma unroll
        for (int off = 1; off < 16; off <<= 1) {
            ps[r] += __shfl_xor(ps[r], off);
            pd[r] += __shfl_xor(pd[r], off);
        }
    }
    if (c == 0) {
        #pragma unroll
        for (int r = 0; r < 4; ++r) {
            pa.hs[rw0 + q * 4 + r] = ps[r] * LOG2E;
            pa.hd[rw0 + q * 4 + r] = pd[r] * LOG2E;
        }
    }
    // bf16 store via per-wave LDS transpose
    #pragma unroll
    for (int t = 0; t < 4; ++t)
        #pragma unroll
        for (int r = 0; r < 4; ++r)
            ctile[w][q * 4 + r][t * 16 + c] = f2bf(acc2[t][r]);
    const int row = lane >> 2, eo = (lane & 3) * 16;
    const uint4 v0 = *(const uint4*)(&ctile[w][row][eo]);
    const uint4 v1 = *(const uint4*)(&ctile[w][row][eo + 8]);
    *(uint4*)(pa.C + (size_t)(rw0 + row) * 64 + eo)     = v0;
    *(uint4*)(pa.C + (size_t)(rw0 + row) * 64 + eo + 8) = v1;
}

// ---------------- CSR build --------------------------------------------------
__global__ __launch_bounds__(256) void edge_hist(
    const int* __restrict__ dst, int* __restrict__ cnt, int e)
{
    const int i0 = (blockIdx.x * 256 + threadIdx.x) * 4;
    if (i0 + 3 < e) {
        const int4 d = *(const int4*)(dst + i0);
        atomicAdd(&cnt[d.x], 1); atomicAdd(&cnt[d.y], 1);
        atomicAdd(&cnt[d.z], 1); atomicAdd(&cnt[d.w], 1);
    } else {
        for (int k = i0; k < e; ++k) atomicAdd(&cnt[dst[k]], 1);
    }
}

__global__ __launch_bounds__(256) void scan1_tiles(
    const int* __restrict__ cnt, int* __restrict__ out,
    int* __restrict__ bsum, int* __restrict__ ticket, int n, int nblk,
    PreArgs pa, int tile0)
{
    __shared__ int wsum[4];
    __shared__ int amLastS;
    if ((int)blockIdx.x >= nblk) {
        gemm_pre_fused(pa, tile0 + (int)blockIdx.x - nblk);
        return;
    }
    const int tid  = threadIdx.x;
    const int lane = tid & 63;
    const int w    = tid >> 6;
    const int base = blockIdx.x * 1024;
    int vals[4];
    int tsum = 0;
    #pragma unroll
    for (int i = 0; i < 4; ++i) {
        const int idx = base + tid * 4 + i;
        vals[i] = (idx < n) ? cnt[idx] : 0;
        tsum += vals[i];
    }
    int x1 = tsum;
    #pragma unroll
    for (int off = 1; off < 64; off <<= 1) {
        const int y = __shfl_up(x1, off);
        if (lane >= off) x1 += y;
    }
    if (lane == 63) wsum[w] = x1;
    __syncthreads();
    int wofs = 0;
    for (int k = 0; k < w; ++k) wofs += wsum[k];
    int excl = wofs + x1 - tsum;
    #pragma unroll
    for (int i = 0; i < 4; ++i) {
        const int idx = base + tid * 4 + i;
        if (idx < n) out[idx] = excl;
        excl += vals[i];
    }
    if (tid == 255) {
        bsum[blockIdx.x] = wofs + x1;
        __threadfence();                       // release bsum write
        amLastS = (atomicAdd(ticket, 1) == nblk - 1) ? 1 : 0;
    }
    __syncthreads();
    if (amLastS) {                             // last block scans bsum[nblk]
        __threadfence();                       // acquire others' bsum writes
        const int v2 = (tid < nblk) ? bsum[tid] : 0;
        int x2 = v2;
        #pragma unroll
        for (int off = 1; off < 64; off <<= 1) {
            const int y = __shfl_up(x2, off);
            if (lane >= off) x2 += y;
        }
        if (lane == 63) wsum[w] = x2;
        __syncthreads();
        int c2 = 0;
        for (int k = 0; k < w; ++k) c2 += wsum[k];
        if (tid < nblk) bsum[tid] = c2 + x2 - v2;
    }
}

__global__ __launch_bounds__(256) void scan3_tiles(
    int* __restrict__ out, const int* __restrict__ bsum,
    int* __restrict__ gcur, int n, int total, int s3b,
    PreArgs pa, int tile0)
{
    if ((int)blockIdx.x >= s3b) {
        gemm_pre_fused(pa, tile0 + (int)blockIdx.x - s3b);
        return;
    }
    const int idx = blockIdx.x * 256 + threadIdx.x;
    if (idx < n) {
        const int v = out[idx] + bsum[idx >> 10];
        out[idx] = v;
        if ((idx & (BKT_N - 1)) == 0) gcur[idx >> BKT_SHIFT] = v;
    }
    if (idx == 0) out[n] = total;
}

__global__ __launch_bounds__(256) void part_tiles(
    const int* __restrict__ src, const int* __restrict__ dst,
    int* __restrict__ gcursor, int* __restrict__ pairs, int e, int nb, int pb,
    PreArgs pa, int tile0)
{
    __shared__ int stage[PCHUNK];
    __shared__ unsigned char sbkt[PCHUNK];
    __shared__ int lcnt[256];
    __shared__ int lstart[256];
    __shared__ int lfill[256];
    __shared__ int gbase[256];
    __shared__ int wsum[4];

    if ((int)blockIdx.x >= pb) {
        gemm_pre_fused(pa, tile0 + (int)blockIdx.x - pb);
        return;
    }

    const int tid  = threadIdx.x;
    const int lane = tid & 63;
    const int w    = tid >> 6;
    const int base = blockIdx.x * PCHUNK;
    const int cnt_here = min(PCHUNK, e - base);

    lcnt[tid] = 0; lfill[tid] = 0;
    __syncthreads();

    for (int i = tid; i < cnt_here; i += 256)
        atomicAdd(&lcnt[dst[base + i] >> BKT_SHIFT], 1);
    __syncthreads();

    const int v = lcnt[tid];
    int x1 = v;
    #pragma unroll
    for (int off = 1; off < 64; off <<= 1) {
        const int y = __shfl_up(x1, off);
        if (lane >= off) x1 += y;
    }
    if (lane == 63) wsum[w] = x1;
    __syncthreads();
    int carry = 0;
    for (int k = 0; k < w; ++k) carry += wsum[k];
    lstart[tid] = carry + x1 - v;
    if (tid < nb && v > 0) gbase[tid] = atomicAdd(&gcursor[tid], v);
    __syncthreads();

    for (int i = tid; i < cnt_here; i += 256) {
        const int d = dst[base + i];
        const int s = src[base + i];
        const int b = d >> BKT_SHIFT;
        const int p = lstart[b] + atomicAdd(&lfill[b], 1);
        stage[p] = ((d & (BKT_N - 1)) << SRC_BITS) | s;
        sbkt[p]  = (unsigned char)b;
    }
    __syncthreads();

    for (int t = tid; t < cnt_here; t += 256) {
        const int b = sbkt[t];
        pairs[gbase[b] + (t - lstart[b])] = stage[t];
    }
}

__global__ __launch_bounds__(256) void scat_tiles(
    const int* __restrict__ pairs, const int* __restrict__ offs,
    int* __restrict__ ssrc, int n, int sb,
    PreArgs pa, int tile0)
{
    __shared__ int pos[BKT_N];
    if ((int)blockIdx.x >= sb) {
        gemm_pre_fused(pa, tile0 + (int)blockIdx.x - sb);
        return;
    }
    const int node0 = blockIdx.x << BKT_SHIFT;
    const int node1 = min(n, node0 + BKT_N);
    const int tid = threadIdx.x;
    for (int i = tid; i < node1 - node0; i += 256) pos[i] = offs[node0 + i];
    __syncthreads();
    const int e0 = offs[node0];
    const int e1 = offs[node1];
    for (int j = e0 + tid; j < e1; j += 256) {
        const int pr = pairs[j];
        const int p = atomicAdd(&pos[pr >> SRC_BITS], 1);
        ssrc[p] = pr & ((1 << SRC_BITS) - 1);
    }
}

// -------- fused aggregate + next-layer GEMM ----------------------------------
// Block = 16 nodes (4 waves x 4 nodes). bf16 rows, 2-deep-index/1-deep-data
// software pipeline (R9 — measured +12% vs plain loop), exp2-form logits,
// 32-bit addressing, dots from fp32 v[].
__global__ __launch_bounds__(256) void fused_ag(
    const ushort* __restrict__ hp, const float* __restrict__ hsIn,
    const float* __restrict__ hdIn, const int* __restrict__ offs,
    const int* __restrict__ ssrc, const float* __restrict__ bias,
    const ushort* __restrict__ WT, const float* __restrict__ waS,
    const float* __restrict__ waD,
    ushort* __restrict__ C, float* __restrict__ hsOut, float* __restrict__ hdOut,
    int n)
{
    __shared__ __align__(16) ushort ldsA[8][16][8];   // [kblk][row][8] bf16
    __shared__ __align__(16) ushort ldsC[16][68];
    const int tid  = threadIdx.x;
    const int w    = tid >> 6, lane = tid & 63;
    const int rw0  = blockIdx.x * 16;
    const int sub  = lane >> 3;
    const int f0   = (lane & 7) * 8;

    const float4 bv0 = *(const float4*)(bias + f0);
    const float4 bv1 = *(const float4*)(bias + f0 + 4);
    const float bb[8] = {bv0.x, bv0.y, bv0.z, bv0.w, bv1.x, bv1.y, bv1.z, bv1.w};
    float ws8[8], wd8[8];
    {
        const float4 s0 = *(const float4*)(waS + f0);
        const float4 s1 = *(const float4*)(waS + f0 + 4);
        const float4 d0 = *(const float4*)(waD + f0);
        const float4 d1 = *(const float4*)(waD + f0 + 4);
        ws8[0]=s0.x; ws8[1]=s0.y; ws8[2]=s0.z; ws8[3]=s0.w;
        ws8[4]=s1.x; ws8[5]=s1.y; ws8[6]=s1.z; ws8[7]=s1.w;
        wd8[0]=d0.x; wd8[1]=d0.y; wd8[2]=d0.z; wd8[3]=d0.w;
        wd8[4]=d1.x; wd8[5]=d1.y; wd8[6]=d1.z; wd8[7]=d1.w;
    }

    #pragma unroll 1
    for (int i = 0; i < 4; ++i) {
        const int rowIdx = w * 4 + i;
        const int node = rw0 + rowIdx;
        if (node < n) {
            const int start = offs[node];
            const int end   = offs[node + 1];
            const float hdi = hdIn[node];

            // index prefetch (two rounds deep)
            int j = start + sub;
            bool vC = j < end;
            bool vN = j + 8 < end;
            int sC = vC ? ssrc[j]     : node;
            int sN = vN ? ssrc[j + 8] : sC;

            float den = 0.f;
            float acc[8] = {};
            if (sub == 0) {   // self-loop
                const uint4 t = *(const uint4*)(hp + (((uint)node << 6) + f0));
                float e = hsIn[node] + hdi;
                e = (e > 0.f) ? e : NEG_SLOPE * e;
                const float ex = exp2f(e);
                float f[8];
                bf2f(t.x, f[0], f[1]); bf2f(t.y, f[2], f[3]);
                bf2f(t.z, f[4], f[5]); bf2f(t.w, f[6], f[7]);
                den = ex;
                #pragma unroll
                for (int k = 0; k < 8; ++k) acc[k] = ex * f[k];
            }

            // data prefetch for round 0
            float hsC = hsIn[sC];
            uint4 tC  = *(const uint4*)(hp + (((uint)sC << 6) + f0));

            while (vC) {
                const bool vNN = j + 16 < end;
                const int  sNN = vNN ? ssrc[j + 16] : sN;   // index 2 ahead
                const float hsN = hsIn[sN];                  // data 1 ahead
                const uint4 tN  = *(const uint4*)(hp + (((uint)sN << 6) + f0));

                float e2 = hsC + hdi;
                e2 = (e2 > 0.f) ? e2 : NEG_SLOPE * e2;
                const float ex2 = exp2f(e2);
                float f[8];
                bf2f(tC.x, f[0], f[1]); bf2f(tC.y, f[2], f[3]);
                bf2f(tC.z, f[4], f[5]); bf2f(tC.w, f[6], f[7]);
                den += ex2;
                #pragma unroll
                for (int k = 0; k < 8; ++k) acc[k] = fmaf(ex2, f[k], acc[k]);

                vC = vN; vN = vNN; sC = sN; sN = sNN; hsC = hsN; tC = tN;
                j += 8;
            }
            #pragma unroll
            for (int off = 8; off < 64; off <<= 1) {
                den += __shfl_xor(den, off);
                #pragma unroll
                for (int k = 0; k < 8; ++k) acc[k] += __shfl_xor(acc[k], off);
            }
            const float inv = 1.f / (den + 1e-16f);
            float v[8];
            #pragma unroll
            for (int k = 0; k < 8; ++k)
                v[k] = fmaxf(acc[k] * inv + bb[k], 0.f);
            // next-layer attn dots from fp32 v
            float psum = 0.f, pdum = 0.f;
            #pragma unroll
            for (int k = 0; k < 8; ++k) {
                psum = fmaf(v[k], ws8[k], psum);
                pdum = fmaf(v[k], wd8[k], pdum);
            }
            #pragma unroll
            for (int off = 1; off < 8; off <<= 1) {
                psum += __shfl_xor(psum, off);
                pdum += __shfl_xor(pdum, off);
            }
            if (lane == 0) { hsOut[node] = psum; hdOut[node] = pdum; }
            if (sub == 0) {
                uint4 o;
                o.x = pk(v[0], v[1]); o.y = pk(v[2], v[3]);
                o.z = pk(v[4], v[5]); o.w = pk(v[6], v[7]);
                *(uint4*)&ldsA[lane & 7][rowIdx][0] = o;
            }
        } else if (sub == 0) {
            const uint4 z = {0u, 0u, 0u, 0u};
            *(uint4*)&ldsA[lane & 7][rowIdx][0] = z;
        }
    }
    __syncthreads();

    // GEMM: wave w -> cols w*16..w*16+15 of h' = a @ W
    const int c = lane & 15, q = lane >> 4;
    const bf16x8 a0 = *(const bf16x8*)&ldsA[q][c][0];
    const bf16x8 a1 = *(const bf16x8*)&ldsA[q + 4][c][0];
    const ushort* bp = WT + (size_t)(w * 16 + c) * 64 + q * 8;
    const bf16x8 b0 = *(const bf16x8*)(bp);
    const bf16x8 b1 = *(const bf16x8*)(bp + 32);
    f32x4 a = (f32x4){0.f, 0.f, 0.f, 0.f};
    a = __builtin_amdgcn_mfma_f32_16x16x32_bf16(a0, b0, a, 0, 0, 0);
    a = __builtin_amdgcn_mfma_f32_16x16x32_bf16(a1, b1, a, 0, 0, 0);
    #pragma unroll
    for (int r = 0; r < 4; ++r)
        ldsC[q * 4 + r][w * 16 + c] = f2bf(a[r]);
    __syncthreads();

    const int row = tid >> 4, co = (tid & 15) * 4;
    if (rw0 + row < n)
        *(uint2*)(C + (size_t)(rw0 + row) * 64 + co) = *(const uint2*)&ldsC[row][co];
}

// ---------------- final gather aggregation (bias + L2 normalize) -------------
__global__ __launch_bounds__(256) void gat_agg_final(
    const ushort* __restrict__ hp, const float* __restrict__ hs,
    const float* __restrict__ hd, const int* __restrict__ offs,
    const int* __restrict__ ssrc, const float* __restrict__ bias,
    float* __restrict__ outp, int n)
{
    const int wid  = (blockIdx.x * blockDim.x + threadIdx.x) >> 6;
    const int lane = threadIdx.x & 63;
    if (wid >= n) return;
    const int sub = lane >> 3;
    const int f0  = (lane & 7) * 8;

    const int start = offs[wid];
    const int end   = offs[wid + 1];
    const float hdi = hd[wid];

    // index prefetch (two rounds deep)
    int j = start + sub;
    bool vC = j < end;
    bool vN = j + 8 < end;
    int sC = vC ? ssrc[j]     : wid;
    int sN = vN ? ssrc[j + 8] : sC;

    float den = 0.f;
    float acc[8] = {};
    if (sub == 0) {
        const uint4 t = *(const uint4*)(hp + (((uint)wid << 6) + f0));
        float e = hs[wid] + hdi;
        e = (e > 0.f) ? e : NEG_SLOPE * e;
        const float ex = exp2f(e);
        float f[8];
        bf2f(t.x, f[0], f[1]); bf2f(t.y, f[2], f[3]);
        bf2f(t.z, f[4], f[5]); bf2f(t.w, f[6], f[7]);
        den = ex;
        #pragma unroll
        for (int i = 0; i < 8; ++i) acc[i] = ex * f[i];
    }

    // data prefetch for round 0
    float hsC = hs[sC];
    uint4 tC  = *(const uint4*)(hp + (((uint)sC << 6) + f0));

    while (vC) {
        const bool vNN = j + 16 < end;
        const int  sNN = vNN ? ssrc[j + 16] : sN;
        const float hsN = hs[sN];
        const uint4 tN  = *(const uint4*)(hp + (((uint)sN << 6) + f0));

        float e2 = hsC + hdi;
        e2 = (e2 > 0.f) ? e2 : NEG_SLOPE * e2;
        const float ex2 = exp2f(e2);
        float f[8];
        bf2f(tC.x, f[0], f[1]); bf2f(tC.y, f[2], f[3]);
        bf2f(tC.z, f[4], f[5]); bf2f(tC.w, f[6], f[7]);
        den += ex2;
        #pragma unroll
        for (int i = 0; i < 8; ++i) acc[i] = fmaf(ex2, f[i], acc[i]);

        vC = vN; vN = vNN; sC = sN; sN = sNN; hsC = hsN; tC = tN;
        j += 8;
    }
    #pragma unroll
    for (int off = 8; off < 64; off <<= 1) {
        den += __shfl_xor(den, off);
        #pragma unroll
        for (int i = 0; i < 8; ++i) acc[i] += __shfl_xor(acc[i], off);
    }
    const float4 bv0 = *(const float4*)(bias + f0);
    const float4 bv1 = *(const float4*)(bias + f0 + 4);
    const float bb[8] = {bv0.x, bv0.y, bv0.z, bv0.w, bv1.x, bv1.y, bv1.z, bv1.w};
    const float inv = 1.f / (den + 1e-16f);
    float v[8];
    #pragma unroll
    for (int i = 0; i < 8; ++i) v[i] = acc[i] * inv + bb[i];
    float sq = 0.f;
    #pragma unroll
    for (int i = 0; i < 8; ++i) sq += v[i] * v[i];
    #pragma unroll
    for (int off = 1; off < 8; off <<= 1) sq += __shfl_xor(sq, off);
    const float s = 1.f / fmaxf(sqrtf(sq), 1e-12f);
    if (sub == 0) {
        float* op = outp + (size_t)wid * 64 + f0;
        float4 o0, o1;
        o0.x = v[0] * s; o0.y = v[1] * s; o0.z = v[2] * s; o0.w = v[3] * s;
        o1.x = v[4] * s; o1.y = v[5] * s; o1.z = v[6] * s; o1.w = v[7] * s;
        *(float4*)(op)     = o0;
        *(float4*)(op + 4) = o1;
    }
}

// ---------------- launch -----------------------------------------------------
extern "C" void kernel_launch(void* const* d_in, const int* in_sizes, int n_in,
                              void* d_out, int out_size, void* d_ws, size_t ws_size,
                              hipStream_t stream)
{
    const float* x     = (const float*)d_in[0];
    const int*   src   = (const int*)d_in[1];
    const int*   dst   = (const int*)d_in[2];
    const float* lin_w = (const float*)d_in[3];
    const float* lin_b = (const float*)d_in[4];
    const float* w1  = (const float*)d_in[5];
    const float* a1s = (const float*)d_in[6];
    const float* a1d = (const float*)d_in[7];
    const float* b1  = (const float*)d_in[8];
    const float* w2  = (const float*)d_in[9];
    const float* a2s = (const float*)d_in[10];
    const float* a2d = (const float*)d_in[11];
    const float* b2  = (const float*)d_in[12];
    const float* w3  = (const float*)d_in[13];
    const float* a3s = (const float*)d_in[14];
    const float* a3d = (const float*)d_in[15];
    const float* b3  = (const float*)d_in[16];

    const int n = in_sizes[0] / 256;   // 100000 nodes
    const int E = in_sizes[1];         // 1280000 edges
    const int nb = (n + BKT_N - 1) >> BKT_SHIFT;   // 196 buckets

    char* wsp = (char*)d_ws;
    auto alloc = [&](size_t bytes) -> void* {
        void* p = (void*)wsp;
        wsp += (bytes + 255) & ~(size_t)255;
        return p;
    };
    ushort* bufA = (ushort*)alloc((size_t)n * 64 * sizeof(ushort));  // bf16 h
    ushort* bufB = (ushort*)alloc((size_t)n * 64 * sizeof(ushort));  // bf16 h'
    float*  hsA  = (float*)alloc((size_t)n * sizeof(float));
    float*  hdA  = (float*)alloc((size_t)n * sizeof(float));
    float*  hsB  = (float*)alloc((size_t)n * sizeof(float));
    float*  hdB  = (float*)alloc((size_t)n * sizeof(float));
    int*    offs = (int*)alloc((size_t)(n + 1) * sizeof(int));
    int*    cnt  = (int*)alloc((size_t)n * sizeof(int));
    int*    bsum = (int*)alloc(1024 * sizeof(int));
    int*    gcur = (int*)alloc(256 * sizeof(int));
    int*    tick = (int*)alloc(256 * sizeof(int));
    int*    ssrc = (int*)alloc((size_t)E * sizeof(int));
    int*    pairs = (int*)alloc((size_t)E * sizeof(int));
    ushort* lwT = (ushort*)alloc(64 * 256 * sizeof(ushort));
    ushort* w1T = (ushort*)alloc(64 * 64 * sizeof(ushort));
    ushort* w2T = (ushort*)alloc(64 * 64 * sizeof(ushort));
    ushort* w3T = (ushort*)alloc(64 * 64 * sizeof(ushort));
    float*  wvec = (float*)alloc(256 * sizeof(float));  // w2aS,w2aD,w3aS,w3aD (x LOG2E)

    const int gemmBlocks = (n + 63) / 64;          // 1563 pre_fused tiles
    const int nScanBlocks = (n + 1023) / 1024;     // 98
    const int s3Blocks = (n + 255) / 256;          // 391
    const int histBlocks = (E / 4 + 255) / 256 + 1;
    const int partBlocks = (E + PCHUNK - 1) / PCHUNK;   // 625
    const int fusedBlocks = (n + 15) / 16;         // 6250
    const int aggBlocks = (n + 3) / 4;             // 25000

    const int TA = 200;                            // tiles in scan1
    const int TB = 300;                            // tiles in scan3
    const int TC = 400;                            // tiles in partition
    const int TD = gemmBlocks - TA - TB - TC;      // tiles in bucket scatter

    PreArgs pa{x, lwT, lin_b, w1T, a1s, a1d, bufB, hsB, hdB, n};

    // ---- weight prep + CSR build with folded h0->h'1 tiles ----
    prep_w<<<(n + 255) / 256, 256, 0, stream>>>(
        lin_w, w1, w2, w3, a2s, a2d, a3s, a3d,
        lwT, w1T, w2T, w3T, wvec, cnt, tick, n);
    edge_hist<<<histBlocks, 256, 0, stream>>>(dst, cnt, E);
    scan1_tiles<<<nScanBlocks + TA, 256, 0, stream>>>(
        cnt, offs, bsum, tick, n, nScanBlocks, pa, 0);
    scan3_tiles<<<s3Blocks + TB, 256, 0, stream>>>(
        offs, bsum, gcur, n, E, s3Blocks, pa, TA);
    part_tiles<<<partBlocks + TC, 256, 0, stream>>>(
        src, dst, gcur, pairs, E, nb, partBlocks, pa, TA + TB);
    scat_tiles<<<nb + TD, 256, 0, stream>>>(
        pairs, offs, ssrc, n, nb, pa, TA + TB + TC);

    // ---- layer 1 agg + layer 2 GEMM ----
    fused_ag<<<fusedBlocks, 256, 0, stream>>>(
        bufB, hsB, hdB, offs, ssrc, b1, w2T, wvec, wvec + 64,
        bufA, hsA, hdA, n);
    // ---- layer 2 agg + layer 3 GEMM ----
    fused_ag<<<fusedBlocks, 256, 0, stream>>>(
        bufA, hsA, hdA, offs, ssrc, b2, w3T, wvec + 128, wvec + 192,
        bufB, hsB, hdB, n);
    // ---- layer 3 agg + normalize -> d_out ----
    gat_agg_final<<<aggBlocks, 256, 0, stream>>>(
        bufB, hsB, hdB, offs, ssrc, b3, (float*)d_out, n);
}

// Round 8
// 435.914 us; speedup vs baseline: 1.1576x; 1.0834x over previous
//
#include <hip/hip_runtime.h>

// GAT 3-layer on MI355X — bf16/MFMA pipeline, R13: bucket-local CSR build.
//   R12 budget: fused_ag x2 =130us, final ~50, prep ~10 -> ~280us sits in the
//   5 build dispatches whose own machinery (per-node hist: 1.28M atomics;
//   two n-sized scans) only exists to produce offs[]. R13 computes offs
//   bucket-locally and deletes edge_hist/scan1/scan3:
//     bhist: per-chunk LDS histogram over 196 BUCKETS -> 196 atomics/chunk
//            (122K total); last block (ticket) scans 196 -> bbase/gcur.
//     part:  unchanged (bucket-partition, packed 4B pairs).
//     scat:  per bucket: LDS hist over 512 local nodes -> LDS scan ->
//            writes offs[node0..) = base+excl -> scatter (pairs reread L2-hot).
//            Single-XCD contiguous ssrc writes preserved (R7 lesson).
//   Aggregation kernels byte-identical to R12 (fused_ag 65us stable x3 rounds:
//   pipeline required (R11), fp32 rows harmful (R10), op-shaving ~free).
//   Dispatches 9 -> 7. gemm_pre_fused tiles redistributed into bhist/part/scat.

constexpr float NEG_SLOPE = 0.2f;
constexpr float LOG2E = 1.4426950408889634f;
#define BKT_SHIFT 9                // 512 nodes per bucket
#define BKT_N     512
#define PCHUNK    2048             // edges staged per partition block
#define SRC_BITS  17               // N=100000 < 2^17

typedef __attribute__((ext_vector_type(8))) short bf16x8;
typedef __attribute__((ext_vector_type(4))) float f32x4;

__device__ inline ushort f2bf(float x) {
    union { float f; uint u; } v; v.f = x;
    return (ushort)((v.u + 0x7FFFu + ((v.u >> 16) & 1u)) >> 16);
}
__device__ inline void bf2f(uint u, float& lo, float& hi) {
    union { uint u; float f; } a, b;
    a.u = u << 16; b.u = u & 0xFFFF0000u;
    lo = a.f; hi = b.f;
}
__device__ inline uint pk(float a, float b) {
    return (uint)f2bf(a) | ((uint)f2bf(b) << 16);
}

struct PreArgs {
    const float* x; const ushort* lwT; const float* lin_b;
    const ushort* w1T; const float* a1s; const float* a1d;
    ushort* C; float* hs; float* hd; int M;
};

// ---------------- weight prep: bf16 transpose + waS/waD + bcnt/ticket zero ---
__global__ __launch_bounds__(256) void prep_w(
    const float* __restrict__ lw, const float* __restrict__ w1,
    const float* __restrict__ w2, const float* __restrict__ w3,
    const float* __restrict__ a2s, const float* __restrict__ a2d,
    const float* __restrict__ a3s, const float* __restrict__ a3d,
    ushort* __restrict__ lwT, ushort* __restrict__ w1T,
    ushort* __restrict__ w2T, ushort* __restrict__ w3T,
    float* __restrict__ wvec,
    int* __restrict__ bcnt, int* __restrict__ ticket)
{
    const int i = blockIdx.x * 256 + threadIdx.x;
    if (i < 256) bcnt[i] = 0;
    if (i == 0) *ticket = 0;
    if (i < 64 * 256) {                 // lwT[n][k] = lw[k][n], K=256
        const int nn = i >> 8, k = i & 255;
        lwT[i] = f2bf(lw[k * 64 + nn]);
    } else if (i < 64 * 256 + 4096) {   // wT[n][k] = w[k][n], K=64
        const int j = i - 64 * 256;
        const int nn = j >> 6, k = j & 63;
        w1T[j] = f2bf(w1[k * 64 + nn]);
        w2T[j] = f2bf(w2[k * 64 + nn]);
        w3T[j] = f2bf(w3[k * 64 + nn]);
    } else if (i < 64 * 256 + 4096 + 256) {
        // wvec[p][k] = LOG2E * sum_n W[k][n]*a[n]; p: 0=w2a2s 1=w2a2d 2=w3a3s 3=w3a3d
        const int j = i - 64 * 256 - 4096;
        const int p = j >> 6, k = j & 63;
        const float* Wp = (p < 2) ? w2 : w3;
        const float* vp = (p == 0) ? a2s : (p == 1) ? a2d : (p == 2) ? a3s : a3d;
        float s = 0.f;
        #pragma unroll
        for (int t = 0; t < 64; ++t) s += Wp[k * 64 + t] * vp[t];
        wvec[p * 64 + k] = s * LOG2E;
    }
}

// ------- gemm_pre_fused tile: h'1 = (x@lw+b)@W1 + attn dots, per 64 rows -----
__device__ __forceinline__ void gemm_pre_fused(const PreArgs& pa, int tile)
{
    __shared__ __align__(16) ushort ldsA[4][8][16][8];   // [wave][kblk][row][8]
    __shared__ __align__(16) ushort ctile[4][16][64];
    const int tid = threadIdx.x;
    const int w = tid >> 6, lane = tid & 63;
    const int rw0 = (tile * 4 + w) * 16;
    if (rw0 >= pa.M) return;
    const int c = lane & 15, q = lane >> 4;

    // ---- stage 1: h0 = x @ lin_w (+ lin_b) ----
    const float* ap = pa.x + (size_t)(rw0 + c) * 256 + q * 8;
    float4 pv[16];
    #pragma unroll
    for (int s = 0; s < 8; ++s) {
        pv[2 * s]     = *(const float4*)(ap + s * 32);
        pv[2 * s + 1] = *(const float4*)(ap + s * 32 + 4);
    }
    f32x4 acc[4];
    #pragma unroll
    for (int t = 0; t < 4; ++t) acc[t] = (f32x4){0.f, 0.f, 0.f, 0.f};
    #pragma unroll
    for (int s = 0; s < 8; ++s) {
        const float4 p0 = pv[2 * s];
        const float4 p1 = pv[2 * s + 1];
        bf16x8 af;
        af[0] = (short)f2bf(p0.x); af[1] = (short)f2bf(p0.y);
        af[2] = (short)f2bf(p0.z); af[3] = (short)f2bf(p0.w);
        af[4] = (short)f2bf(p1.x); af[5] = (short)f2bf(p1.y);
        af[6] = (short)f2bf(p1.z); af[7] = (short)f2bf(p1.w);
        #pragma unroll
        for (int t = 0; t < 4; ++t) {
            const bf16x8 bf = *(const bf16x8*)(pa.lwT + (size_t)(t * 16 + c) * 256 + s * 32 + q * 8);
            acc[t] = __builtin_amdgcn_mfma_f32_16x16x32_bf16(af, bf, acc[t], 0, 0, 0);
        }
    }
    // round h0+bias into fragment-layout LDS (row=q*4+r, col=16t+c)
    #pragma unroll
    for (int t = 0; t < 4; ++t) {
        const float bv = pa.lin_b[t * 16 + c];
        const int kb = 2 * t + (c >> 3);
        const int e  = c & 7;
        #pragma unroll
        for (int r = 0; r < 4; ++r)
            ldsA[w][kb][q * 4 + r][e] = f2bf(acc[t][r] + bv);
    }

    // ---- stage 2: h'1 = h0 @ W1 (+ dots) ----  (same-wave LDS RAW: DS in-order)
    const bf16x8 a0 = *(const bf16x8*)&ldsA[w][q][c][0];
    const bf16x8 a1 = *(const bf16x8*)&ldsA[w][q + 4][c][0];
    f32x4 acc2[4];
    #pragma unroll
    for (int t = 0; t < 4; ++t) {
        const ushort* bp = pa.w1T + (size_t)(t * 16 + c) * 64 + q * 8;
        const bf16x8 b0 = *(const bf16x8*)(bp);
        const bf16x8 b1 = *(const bf16x8*)(bp + 32);
        f32x4 a = (f32x4){0.f, 0.f, 0.f, 0.f};
        a = __builtin_amdgcn_mfma_f32_16x16x32_bf16(a0, b0, a, 0, 0, 0);
        a = __builtin_amdgcn_mfma_f32_16x16x32_bf16(a1, b1, a, 0, 0, 0);
        acc2[t] = a;
    }
    // attn dots (scaled by LOG2E for exp2 in the gather)
    float ps[4] = {0.f, 0.f, 0.f, 0.f}, pd[4] = {0.f, 0.f, 0.f, 0.f};
    #pragma unroll
    for (int t = 0; t < 4; ++t) {
        const float as = pa.a1s[t * 16 + c], ad = pa.a1d[t * 16 + c];
        #pragma unroll
        for (int r = 0; r < 4; ++r) {
            ps[r] = fmaf(acc2[t][r], as, ps[r]);
            pd[r] = fmaf(acc2[t][r], ad, pd[r]);
        }
    }
    #pragma unroll
    for (int r = 0; r < 4; ++r) {
        #pragma unroll
        for (int off = 1; off < 16; off <<= 1) {
            ps[r] += __shfl_xor(ps[r], off);
            pd[r] += __shfl_xor(pd[r], off);
        }
    }
    if (c == 0) {
        #pragma unroll
        for (int r = 0; r < 4; ++r) {
            pa.hs[rw0 + q * 4 + r] = ps[r] * LOG2E;
            pa.hd[rw0 + q * 4 + r] = pd[r] * LOG2E;
        }
    }
    // bf16 store via per-wave LDS transpose
    #pragma unroll
    for (int t = 0; t < 4; ++t)
        #pragma unroll
        for (int r = 0; r < 4; ++r)
            ctile[w][q * 4 + r][t * 16 + c] = f2bf(acc2[t][r]);
    const int row = lane >> 2, eo = (lane & 3) * 16;
    const uint4 v0 = *(const uint4*)(&ctile[w][row][eo]);
    const uint4 v1 = *(const uint4*)(&ctile[w][row][eo + 8]);
    *(uint4*)(pa.C + (size_t)(rw0 + row) * 64 + eo)     = v0;
    *(uint4*)(pa.C + (size_t)(rw0 + row) * 64 + eo + 8) = v1;
}

// ------------- bhist (+ tiles): per-chunk bucket histogram -------------------
// LDS hist over 196 buckets; 196 global atomics per chunk. Last chunk block
// (device-scope ticket) scans bcnt[nb] -> bbase[0..nb] and partition cursors.
__global__ __launch_bounds__(256) void bhist_tiles(
    const int* __restrict__ dst, int* __restrict__ bcnt,
    int* __restrict__ bbase, int* __restrict__ gcur, int* __restrict__ ticket,
    int e, int nb, int nchunks, PreArgs pa, int tile0)
{
    __shared__ int lcnt[256];
    __shared__ int wsum[4];
    __shared__ int amLastS;
    if ((int)blockIdx.x >= nchunks) {
        gemm_pre_fused(pa, tile0 + (int)blockIdx.x - nchunks);
        return;
    }
    const int tid  = threadIdx.x;
    const int lane = tid & 63;
    const int w    = tid >> 6;
    const int base = blockIdx.x * PCHUNK;
    const int cnt_here = min(PCHUNK, e - base);

    lcnt[tid] = 0;
    __syncthreads();
    for (int i = tid; i < cnt_here; i += 256)
        atomicAdd(&lcnt[dst[base + i] >> BKT_SHIFT], 1);
    __syncthreads();
    if (tid < nb && lcnt[tid] > 0) atomicAdd(&bcnt[tid], lcnt[tid]);
    __syncthreads();
    if (tid == 0) {
        __threadfence();                       // release our bcnt adds
        amLastS = (atomicAdd(ticket, 1) == nchunks - 1) ? 1 : 0;
    }
    __syncthreads();
    if (amLastS) {                             // last block: scan bcnt[nb]
        __threadfence();                       // acquire others' bcnt adds
        const int v = (tid < nb) ? bcnt[tid] : 0;
        int x1 = v;
        #pragma unroll
        for (int off = 1; off < 64; off <<= 1) {
            const int y = __shfl_up(x1, off);
            if (lane >= off) x1 += y;
        }
        if (lane == 63) wsum[w] = x1;
        __syncthreads();
        int carry = 0;
        for (int k = 0; k < w; ++k) carry += wsum[k];
        const int excl = carry + x1 - v;
        if (tid < nb) { bbase[tid] = excl; gcur[tid] = excl; }
        if (tid == 0) bbase[nb] = e;
    }
}

// ------------- part (+ tiles): bucket-partition, packed 4B pairs -------------
__global__ __launch_bounds__(256) void part_tiles(
    const int* __restrict__ src, const int* __restrict__ dst,
    int* __restrict__ gcursor, int* __restrict__ pairs, int e, int nb, int pb,
    PreArgs pa, int tile0)
{
    __shared__ int stage[PCHUNK];
    __shared__ unsigned char sbkt[PCHUNK];
    __shared__ int lcnt[256];
    __shared__ int lstart[256];
    __shared__ int lfill[256];
    __shared__ int gbase[256];
    __shared__ int wsum[4];

    if ((int)blockIdx.x >= pb) {
        gemm_pre_fused(pa, tile0 + (int)blockIdx.x - pb);
        return;
    }

    const int tid  = threadIdx.x;
    const int lane = tid & 63;
    const int w    = tid >> 6;
    const int base = blockIdx.x * PCHUNK;
    const int cnt_here = min(PCHUNK, e - base);

    lcnt[tid] = 0; lfill[tid] = 0;
    __syncthreads();

    for (int i = tid; i < cnt_here; i += 256)
        atomicAdd(&lcnt[dst[base + i] >> BKT_SHIFT], 1);
    __syncthreads();

    const int v = lcnt[tid];
    int x1 = v;
    #pragma unroll
    for (int off = 1; off < 64; off <<= 1) {
        const int y = __shfl_up(x1, off);
        if (lane >= off) x1 += y;
    }
    if (lane == 63) wsum[w] = x1;
    __syncthreads();
    int carry = 0;
    for (int k = 0; k < w; ++k) carry += wsum[k];
    lstart[tid] = carry + x1 - v;
    if (tid < nb && v > 0) gbase[tid] = atomicAdd(&gcursor[tid], v);
    __syncthreads();

    for (int i = tid; i < cnt_here; i += 256) {
        const int d = dst[base + i];
        const int s = src[base + i];
        const int b = d >> BKT_SHIFT;
        const int p = lstart[b] + atomicAdd(&lfill[b], 1);
        stage[p] = ((d & (BKT_N - 1)) << SRC_BITS) | s;
        sbkt[p]  = (unsigned char)b;
    }
    __syncthreads();

    for (int t = tid; t < cnt_here; t += 256) {
        const int b = sbkt[t];
        pairs[gbase[b] + (t - lstart[b])] = stage[t];
    }
}

// ------------- scat (+ tiles): bucket-local hist+scan -> offs + scatter ------
// One block per bucket. Pass1 counts local nodes (LDS atomics; pairs pulled
// into this XCD's L2), LDS-scan 512 -> offs[node0..), pass2 scatters via LDS
// cursors (pairs reread L2-hot). Writes stay in this bucket's contiguous
// ssrc region (single-XCD line merging).
__global__ __launch_bounds__(256) void scat_tiles(
    const int* __restrict__ pairs, const int* __restrict__ bbase,
    int* __restrict__ offs, int* __restrict__ ssrc, int n, int nb,
    PreArgs pa, int tile0)
{
    __shared__ int lcnt[BKT_N];
    __shared__ int lofs[BKT_N];
    __shared__ int wsum[4];
    if ((int)blockIdx.x >= nb) {
        gemm_pre_fused(pa, tile0 + (int)blockIdx.x - nb);
        return;
    }
    const int b     = blockIdx.x;
    const int tid   = threadIdx.x;
    const int lane  = tid & 63;
    const int w     = tid >> 6;
    const int node0 = b << BKT_SHIFT;
    const int nlocal = min(n - node0, BKT_N);
    const int e0 = bbase[b];
    const int e1 = bbase[b + 1];

    lcnt[tid] = 0; lcnt[tid + 256] = 0;
    __syncthreads();

    // pass 1: count local nodes
    for (int j = e0 + tid; j < e1; j += 256)
        atomicAdd(&lcnt[pairs[j] >> SRC_BITS], 1);
    __syncthreads();

    // exclusive scan of lcnt[512] (2 values/thread) -> lofs = e0 + excl
    const int v0 = lcnt[2 * tid], v1 = lcnt[2 * tid + 1];
    const int tsum = v0 + v1;
    int x1 = tsum;
    #pragma unroll
    for (int off = 1; off < 64; off <<= 1) {
        const int y = __shfl_up(x1, off);
        if (lane >= off) x1 += y;
    }
    if (lane == 63) wsum[w] = x1;
    __syncthreads();
    int carry = 0;
    for (int k = 0; k < w; ++k) carry += wsum[k];
    const int excl = carry + x1 - tsum;
    lofs[2 * tid]     = e0 + excl;
    lofs[2 * tid + 1] = e0 + excl + v0;
    __syncthreads();

    // write CSR offsets for this bucket
    for (int i = tid; i < nlocal; i += 256) offs[node0 + i] = lofs[i];
    if (b == nb - 1 && tid == 0) offs[n] = e1;
    __syncthreads();   // offs reads of lofs done before cursors mutate

    // pass 2: scatter (pairs reread is L2-hot)
    for (int j = e0 + tid; j < e1; j += 256) {
        const int pr = pairs[j];
        const int p = atomicAdd(&lofs[pr >> SRC_BITS], 1);
        ssrc[p] = pr & ((1 << SRC_BITS) - 1);
    }
}

// -------- fused aggregate + next-layer GEMM (unchanged from R12) -------------
__global__ __launch_bounds__(256) void fused_ag(
    const ushort* __restrict__ hp, const float* __restrict__ hsIn,
    const float* __restrict__ hdIn, const int* __restrict__ offs,
    const int* __restrict__ ssrc, const float* __restrict__ bias,
    const ushort* __restrict__ WT, const float* __restrict__ waS,
    const float* __restrict__ waD,
    ushort* __restrict__ C, float* __restrict__ hsOut, float* __restrict__ hdOut,
    int n)
{
    __shared__ __align__(16) ushort ldsA[8][16][8];   // [kblk][row][8] bf16
    __shared__ __align__(16) ushort ldsC[16][68];
    const int tid  = threadIdx.x;
    const int w    = tid >> 6, lane = tid & 63;
    const int rw0  = blockIdx.x * 16;
    const int sub  = lane >> 3;
    const int f0   = (lane & 7) * 8;

    const float4 bv0 = *(const float4*)(bias + f0);
    const float4 bv1 = *(const float4*)(bias + f0 + 4);
    const float bb[8] = {bv0.x, bv0.y, bv0.z, bv0.w, bv1.x, bv1.y, bv1.z, bv1.w};
    float ws8[8], wd8[8];
    {
        const float4 s0 = *(const float4*)(waS + f0);
        const float4 s1 = *(const float4*)(waS + f0 + 4);
        const float4 d0 = *(const float4*)(waD + f0);
        const float4 d1 = *(const float4*)(waD + f0 + 4);
        ws8[0]=s0.x; ws8[1]=s0.y; ws8[2]=s0.z; ws8[3]=s0.w;
        ws8[4]=s1.x; ws8[5]=s1.y; ws8[6]=s1.z; ws8[7]=s1.w;
        wd8[0]=d0.x; wd8[1]=d0.y; wd8[2]=d0.z; wd8[3]=d0.w;
        wd8[4]=d1.x; wd8[5]=d1.y; wd8[6]=d1.z; wd8[7]=d1.w;
    }

    #pragma unroll 1
    for (int i = 0; i < 4; ++i) {
        const int rowIdx = w * 4 + i;
        const int node = rw0 + rowIdx;
        if (node < n) {
            const int start = offs[node];
            const int end   = offs[node + 1];
            const float hdi = hdIn[node];

            // index prefetch (two rounds deep)
            int j = start + sub;
            bool vC = j < end;
            bool vN = j + 8 < end;
            int sC = vC ? ssrc[j]     : node;
            int sN = vN ? ssrc[j + 8] : sC;

            float den = 0.f;
            float acc[8] = {};
            if (sub == 0) {   // self-loop
                const uint4 t = *(const uint4*)(hp + (((uint)node << 6) + f0));
                float e = hsIn[node] + hdi;
                e = (e > 0.f) ? e : NEG_SLOPE * e;
                const float ex = exp2f(e);
                float f[8];
                bf2f(t.x, f[0], f[1]); bf2f(t.y, f[2], f[3]);
                bf2f(t.z, f[4], f[5]); bf2f(t.w, f[6], f[7]);
                den = ex;
                #pragma unroll
                for (int k = 0; k < 8; ++k) acc[k] = ex * f[k];
            }

            // data prefetch for round 0
            float hsC = hsIn[sC];
            uint4 tC  = *(const uint4*)(hp + (((uint)sC << 6) + f0));

            while (vC) {
                const bool vNN = j + 16 < end;
                const int  sNN = vNN ? ssrc[j + 16] : sN;   // index 2 ahead
                const float hsN = hsIn[sN];                  // data 1 ahead
                const uint4 tN  = *(const uint4*)(hp + (((uint)sN << 6) + f0));

                float e2 = hsC + hdi;
                e2 = (e2 > 0.f) ? e2 : NEG_SLOPE * e2;
                const float ex2 = exp2f(e2);
                float f[8];
                bf2f(tC.x, f[0], f[1]); bf2f(tC.y, f[2], f[3]);
                bf2f(tC.z, f[4], f[5]); bf2f(tC.w, f[6], f[7]);
                den += ex2;
                #pragma unroll
                for (int k = 0; k < 8; ++k) acc[k] = fmaf(ex2, f[k], acc[k]);

                vC = vN; vN = vNN; sC = sN; sN = sNN; hsC = hsN; tC = tN;
                j += 8;
            }
            #pragma unroll
            for (int off = 8; off < 64; off <<= 1) {
                den += __shfl_xor(den, off);
                #pragma unroll
                for (int k = 0; k < 8; ++k) acc[k] += __shfl_xor(acc[k], off);
            }
            const float inv = 1.f / (den + 1e-16f);
            float v[8];
            #pragma unroll
            for (int k = 0; k < 8; ++k)
                v[k] = fmaxf(acc[k] * inv + bb[k], 0.f);
            // next-layer attn dots from fp32 v
            float psum = 0.f, pdum = 0.f;
            #pragma unroll
            for (int k = 0; k < 8; ++k) {
                psum = fmaf(v[k], ws8[k], psum);
                pdum = fmaf(v[k], wd8[k], pdum);
            }
            #pragma unroll
            for (int off = 1; off < 8; off <<= 1) {
                psum += __shfl_xor(psum, off);
                pdum += __shfl_xor(pdum, off);
            }
            if (lane == 0) { hsOut[node] = psum; hdOut[node] = pdum; }
            if (sub == 0) {
                uint4 o;
                o.x = pk(v[0], v[1]); o.y = pk(v[2], v[3]);
                o.z = pk(v[4], v[5]); o.w = pk(v[6], v[7]);
                *(uint4*)&ldsA[lane & 7][rowIdx][0] = o;
            }
        } else if (sub == 0) {
            const uint4 z = {0u, 0u, 0u, 0u};
            *(uint4*)&ldsA[lane & 7][rowIdx][0] = z;
        }
    }
    __syncthreads();

    // GEMM: wave w -> cols w*16..w*16+15 of h' = a @ W
    const int c = lane & 15, q = lane >> 4;
    const bf16x8 a0 = *(const bf16x8*)&ldsA[q][c][0];
    const bf16x8 a1 = *(const bf16x8*)&ldsA[q + 4][c][0];
    const ushort* bp = WT + (size_t)(w * 16 + c) * 64 + q * 8;
    const bf16x8 b0 = *(const bf16x8*)(bp);
    const bf16x8 b1 = *(const bf16x8*)(bp + 32);
    f32x4 a = (f32x4){0.f, 0.f, 0.f, 0.f};
    a = __builtin_amdgcn_mfma_f32_16x16x32_bf16(a0, b0, a, 0, 0, 0);
    a = __builtin_amdgcn_mfma_f32_16x16x32_bf16(a1, b1, a, 0, 0, 0);
    #pragma unroll
    for (int r = 0; r < 4; ++r)
        ldsC[q * 4 + r][w * 16 + c] = f2bf(a[r]);
    __syncthreads();

    const int row = tid >> 4, co = (tid & 15) * 4;
    if (rw0 + row < n)
        *(uint2*)(C + (size_t)(rw0 + row) * 64 + co) = *(const uint2*)&ldsC[row][co];
}

// ------- final gather aggregation (bias + L2 normalize), unchanged R12 -------
__global__ __launch_bounds__(256) void gat_agg_final(
    const ushort* __restrict__ hp, const float* __restrict__ hs,
    const float* __restrict__ hd, const int* __restrict__ offs,
    const int* __restrict__ ssrc, const float* __restrict__ bias,
    float* __restrict__ outp, int n)
{
    const int wid  = (blockIdx.x * blockDim.x + threadIdx.x) >> 6;
    const int lane = threadIdx.x & 63;
    if (wid >= n) return;
    const int sub = lane >> 3;
    const int f0  = (lane & 7) * 8;

    const int start = offs[wid];
    const int end   = offs[wid + 1];
    const float hdi = hd[wid];

    // index prefetch (two rounds deep)
    int j = start + sub;
    bool vC = j < end;
    bool vN = j + 8 < end;
    int sC = vC ? ssrc[j]     : wid;
    int sN = vN ? ssrc[j + 8] : sC;

    float den = 0.f;
    float acc[8] = {};
    if (sub == 0) {
        const uint4 t = *(const uint4*)(hp + (((uint)wid << 6) + f0));
        float e = hs[wid] + hdi;
        e = (e > 0.f) ? e : NEG_SLOPE * e;
        const float ex = exp2f(e);
        float f[8];
        bf2f(t.x, f[0], f[1]); bf2f(t.y, f[2], f[3]);
        bf2f(t.z, f[4], f[5]); bf2f(t.w, f[6], f[7]);
        den = ex;
        #pragma unroll
        for (int i = 0; i < 8; ++i) acc[i] = ex * f[i];
    }

    // data prefetch for round 0
    float hsC = hs[sC];
    uint4 tC  = *(const uint4*)(hp + (((uint)sC << 6) + f0));

    while (vC) {
        const bool vNN = j + 16 < end;
        const int  sNN = vNN ? ssrc[j + 16] : sN;
        const float hsN = hs[sN];
        const uint4 tN  = *(const uint4*)(hp + (((uint)sN << 6) + f0));

        float e2 = hsC + hdi;
        e2 = (e2 > 0.f) ? e2 : NEG_SLOPE * e2;
        const float ex2 = exp2f(e2);
        float f[8];
        bf2f(tC.x, f[0], f[1]); bf2f(tC.y, f[2], f[3]);
        bf2f(tC.z, f[4], f[5]); bf2f(tC.w, f[6], f[7]);
        den += ex2;
        #pragma unroll
        for (int i = 0; i < 8; ++i) acc[i] = fmaf(ex2, f[i], acc[i]);

        vC = vN; vN = vNN; sC = sN; sN = sNN; hsC = hsN; tC = tN;
        j += 8;
    }
    #pragma unroll
    for (int off = 8; off < 64; off <<= 1) {
        den += __shfl_xor(den, off);
        #pragma unroll
        for (int i = 0; i < 8; ++i) acc[i] += __shfl_xor(acc[i], off);
    }
    const float4 bv0 = *(const float4*)(bias + f0);
    const float4 bv1 = *(const float4*)(bias + f0 + 4);
    const float bb[8] = {bv0.x, bv0.y, bv0.z, bv0.w, bv1.x, bv1.y, bv1.z, bv1.w};
    const float inv = 1.f / (den + 1e-16f);
    float v[8];
    #pragma unroll
    for (int i = 0; i < 8; ++i) v[i] = acc[i] * inv + bb[i];
    float sq = 0.f;
    #pragma unroll
    for (int i = 0; i < 8; ++i) sq += v[i] * v[i];
    #pragma unroll
    for (int off = 1; off < 8; off <<= 1) sq += __shfl_xor(sq, off);
    const float s = 1.f / fmaxf(sqrtf(sq), 1e-12f);
    if (sub == 0) {
        float* op = outp + (size_t)wid * 64 + f0;
        float4 o0, o1;
        o0.x = v[0] * s; o0.y = v[1] * s; o0.z = v[2] * s; o0.w = v[3] * s;
        o1.x = v[4] * s; o1.y = v[5] * s; o1.z = v[6] * s; o1.w = v[7] * s;
        *(float4*)(op)     = o0;
        *(float4*)(op + 4) = o1;
    }
}

// ---------------- launch -----------------------------------------------------
extern "C" void kernel_launch(void* const* d_in, const int* in_sizes, int n_in,
                              void* d_out, int out_size, void* d_ws, size_t ws_size,
                              hipStream_t stream)
{
    const float* x     = (const float*)d_in[0];
    const int*   src   = (const int*)d_in[1];
    const int*   dst   = (const int*)d_in[2];
    const float* lin_w = (const float*)d_in[3];
    const float* lin_b = (const float*)d_in[4];
    const float* w1  = (const float*)d_in[5];
    const float* a1s = (const float*)d_in[6];
    const float* a1d = (const float*)d_in[7];
    const float* b1  = (const float*)d_in[8];
    const float* w2  = (const float*)d_in[9];
    const float* a2s = (const float*)d_in[10];
    const float* a2d = (const float*)d_in[11];
    const float* b2  = (const float*)d_in[12];
    const float* w3  = (const float*)d_in[13];
    const float* a3s = (const float*)d_in[14];
    const float* a3d = (const float*)d_in[15];
    const float* b3  = (const float*)d_in[16];

    const int n = in_sizes[0] / 256;   // 100000 nodes
    const int E = in_sizes[1];         // 1280000 edges
    const int nb = (n + BKT_N - 1) >> BKT_SHIFT;   // 196 buckets

    char* wsp = (char*)d_ws;
    auto alloc = [&](size_t bytes) -> void* {
        void* p = (void*)wsp;
        wsp += (bytes + 255) & ~(size_t)255;
        return p;
    };
    ushort* bufA = (ushort*)alloc((size_t)n * 64 * sizeof(ushort));  // bf16 h
    ushort* bufB = (ushort*)alloc((size_t)n * 64 * sizeof(ushort));  // bf16 h'
    float*  hsA  = (float*)alloc((size_t)n * sizeof(float));
    float*  hdA  = (float*)alloc((size_t)n * sizeof(float));
    float*  hsB  = (float*)alloc((size_t)n * sizeof(float));
    float*  hdB  = (float*)alloc((size_t)n * sizeof(float));
    int*    offs = (int*)alloc((size_t)(n + 1) * sizeof(int));
    int*    bcnt = (int*)alloc(256 * sizeof(int));
    int*    bbase = (int*)alloc(257 * sizeof(int));
    int*    gcur = (int*)alloc(256 * sizeof(int));
    int*    tick = (int*)alloc(256 * sizeof(int));
    int*    ssrc = (int*)alloc((size_t)E * sizeof(int));
    int*    pairs = (int*)alloc((size_t)E * sizeof(int));
    ushort* lwT = (ushort*)alloc(64 * 256 * sizeof(ushort));
    ushort* w1T = (ushort*)alloc(64 * 64 * sizeof(ushort));
    ushort* w2T = (ushort*)alloc(64 * 64 * sizeof(ushort));
    ushort* w3T = (ushort*)alloc(64 * 64 * sizeof(ushort));
    float*  wvec = (float*)alloc(256 * sizeof(float));  // w2aS,w2aD,w3aS,w3aD (x LOG2E)

    const int gemmBlocks = (n + 63) / 64;          // 1563 pre_fused tiles
    const int partBlocks = (E + PCHUNK - 1) / PCHUNK;   // 625 chunks
    const int fusedBlocks = (n + 15) / 16;         // 6250
    const int aggBlocks = (n + 3) / 4;             // 25000

    const int TA = 400;                            // tiles in bhist
    const int TB = 500;                            // tiles in part
    const int TC = gemmBlocks - TA - TB;           // tiles in scat (663)

    PreArgs pa{x, lwT, lin_b, w1T, a1s, a1d, bufB, hsB, hdB, n};

    // ---- weight prep + bucket-local CSR build with folded h0->h'1 tiles ----
    prep_w<<<(64 * 256 + 4096 + 256 + 255) / 256, 256, 0, stream>>>(
        lin_w, w1, w2, w3, a2s, a2d, a3s, a3d,
        lwT, w1T, w2T, w3T, wvec, bcnt, tick);
    bhist_tiles<<<partBlocks + TA, 256, 0, stream>>>(
        dst, bcnt, bbase, gcur, tick, E, nb, partBlocks, pa, 0);
    part_tiles<<<partBlocks + TB, 256, 0, stream>>>(
        src, dst, gcur, pairs, E, nb, partBlocks, pa, TA);
    scat_tiles<<<nb + TC, 256, 0, stream>>>(
        pairs, bbase, offs, ssrc, n, nb, pa, TA + TB);

    // ---- layer 1 agg + layer 2 GEMM ----
    fused_ag<<<fusedBlocks, 256, 0, stream>>>(
        bufB, hsB, hdB, offs, ssrc, b1, w2T, wvec, wvec + 64,
        bufA, hsA, hdA, n);
    // ---- layer 2 agg + layer 3 GEMM ----
    fused_ag<<<fusedBlocks, 256, 0, stream>>>(
        bufA, hsA, hdA, offs, ssrc, b2, w3T, wvec + 128, wvec + 192,
        bufB, hsB, hdB, n);
    // ---- layer 3 agg + normalize -> d_out ----
    gat_agg_final<<<aggBlocks, 256, 0, stream>>>(
        bufB, hsB, hdB, offs, ssrc, b3, (float*)d_out, n);
}